// Round 3
// baseline (850.680 us; speedup 1.0000x reference)
//
#include <hip/hip_runtime.h>
#include <stdint.h>

#define N_NODES 100000
#define N_EDGES 1600000
#define IN_DIM  128
#define HID_DIM 256
#define OUT_DIM 128
#define RS 264   // padded LDS row stride (bf16 elems); 264*2=528 B, 528%16==0

typedef __attribute__((ext_vector_type(8))) short bf16x8;
typedef __attribute__((ext_vector_type(4))) float f32x4;

__device__ __forceinline__ float bf2f(uint16_t h) {
    union { uint32_t u; float f; } c; c.u = ((uint32_t)h) << 16; return c.f;
}
__device__ __forceinline__ uint16_t f2bf(float f) {
    union { float f; uint32_t u; } c; c.f = f;
    uint32_t u = c.u;
    return (uint16_t)((u + 0x7fffu + ((u >> 16) & 1u)) >> 16);  // RNE
}
__device__ __forceinline__ int clampi(int v) {
    v = v < 0 ? 0 : v;
    return v >= N_NODES ? N_NODES - 1 : v;
}

// ---------------- int64-vs-int32 edge_index detection ----------------
// int64 little-endian nonneg < 2^31: odd dwords are all 0.

__global__ void detect_kernel(const int* __restrict__ ei, int* __restrict__ flag) {
    if (threadIdx.x == 0 && blockIdx.x == 0) {
        int z = 1;
        for (int i = 0; i < 16; ++i)
            if (ei[2 * i + 1] != 0) z = 0;
        flag[0] = z;
    }
}

__device__ __forceinline__ int src_at(const int* ei, int isI64, int e) {
    return clampi(isI64 ? ei[2 * (size_t)e] : ei[e]);
}
__device__ __forceinline__ int dst_at(const int* ei, int isI64, int e) {
    return clampi(isI64 ? ei[2 * (size_t)N_EDGES + 2 * (size_t)e]
                        : ei[(size_t)N_EDGES + e]);
}

// ---------------- CSR construction ----------------

__global__ __launch_bounds__(256) void count_kernel(const int* __restrict__ ei,
                                                    const int* __restrict__ flag,
                                                    int* __restrict__ cnt) {
    int e = blockIdx.x * 256 + threadIdx.x;
    if (e < N_EDGES) atomicAdd(&cnt[dst_at(ei, flag[0], e)], 1);
}

__global__ __launch_bounds__(256) void scan_a(const int* __restrict__ cnt,
                                              int* __restrict__ row_ptr,
                                              int* __restrict__ bsum, int n) {
    __shared__ int lds[256];
    int t = threadIdx.x, g = blockIdx.x * 256 + t;
    int v = (g < n) ? cnt[g] : 0;
    lds[t] = v; __syncthreads();
    for (int off = 1; off < 256; off <<= 1) {
        int x = (t >= off) ? lds[t - off] : 0;
        __syncthreads();
        if (t >= off) lds[t] += x;
        __syncthreads();
    }
    if (g < n) row_ptr[g] = lds[t] - v;     // exclusive
    if (t == 255) bsum[blockIdx.x] = lds[t];
}

__global__ __launch_bounds__(512) void scan_b(int* __restrict__ bsum, int nb) {
    __shared__ int lds[512];
    int t = threadIdx.x;
    int v = (t < nb) ? bsum[t] : 0;
    lds[t] = v; __syncthreads();
    for (int off = 1; off < 512; off <<= 1) {
        int x = (t >= off) ? lds[t - off] : 0;
        __syncthreads();
        if (t >= off) lds[t] += x;
        __syncthreads();
    }
    if (t < nb) bsum[t] = lds[t] - v;       // exclusive
}

__global__ __launch_bounds__(256) void scan_c(int* __restrict__ row_ptr,
                                              const int* __restrict__ bsum,
                                              int n, int total) {
    int g = blockIdx.x * 256 + threadIdx.x;
    if (g < n) row_ptr[g] += bsum[blockIdx.x];
    if (g == 0) row_ptr[n] = total;
}

__global__ __launch_bounds__(256) void finalize_kernel(const int* __restrict__ cnt,
                                                       const int* __restrict__ row_ptr,
                                                       int* __restrict__ cursor,
                                                       float* __restrict__ dinv) {
    int i = blockIdx.x * 256 + threadIdx.x;
    if (i < N_NODES) {
        cursor[i] = row_ptr[i];
        dinv[i] = rsqrtf((float)(cnt[i] + 1));  // +1 self-loop; always > 0
    }
}

__global__ __launch_bounds__(256) void fill_kernel(const int* __restrict__ ei,
                                                   const int* __restrict__ flag,
                                                   int* __restrict__ cursor,
                                                   int* __restrict__ colv) {
    int e = blockIdx.x * 256 + threadIdx.x;
    if (e < N_EDGES) {
        int isI64 = flag[0];
        int slot = atomicAdd(&cursor[dst_at(ei, isI64, e)], 1);
        colv[slot] = src_at(ei, isI64, e);
    }
}

// ---------------- weight transpose + hi/lo bf16 split ----------------
// W[k][n] fp32 -> Wh/Wl[n][k] bf16 with W ~= hi + lo (~2^-17 rel err)

__global__ __launch_bounds__(256) void wsplit_kernel(const float* __restrict__ W,
                                                     uint16_t* __restrict__ Wh,
                                                     uint16_t* __restrict__ Wl,
                                                     int K, int N) {
    int idx = blockIdx.x * 256 + threadIdx.x;
    if (idx < K * N) {
        int k = idx / N, n = idx - k * N;
        float v = W[idx];
        uint16_t h = f2bf(v);
        Wh[n * K + k] = h;
        Wl[n * K + k] = f2bf(v - bf2f(h));
    }
}

// ---------------- normalized aggregation (128-dim fp32 rows) ----------------
// out[i] = dinv[i] * ( sum_{e: s->i} dinv[s]*feat[s] + dinv[i]*feat[i] )
// LN=true: + bias, then LayerNorm(gamma,beta)

template<bool LN>
__global__ __launch_bounds__(256) void agg_kernel(const float* __restrict__ feat,
                                                  const int* __restrict__ row_ptr,
                                                  const int* __restrict__ colv,
                                                  const float* __restrict__ dinv,
                                                  const float* __restrict__ bias,
                                                  const float* __restrict__ gamma,
                                                  const float* __restrict__ beta,
                                                  float* __restrict__ out) {
    int node = blockIdx.x * 4 + (threadIdx.x >> 6);
    if (node >= N_NODES) return;
    int lane = threadIdx.x & 63;
    float di = dinv[node];
    const float2* base = (const float2*)feat;
    float2 u = base[(size_t)node * 64 + lane];
    float acc0 = di * u.x, acc1 = di * u.y;   // self-loop term
    int e = row_ptr[node], e1 = row_ptr[node + 1];
    for (; e < e1; ++e) {
        int s = clampi(colv[e]);
        float w = dinv[s];
        float2 v = base[(size_t)s * 64 + lane];
        acc0 += w * v.x;
        acc1 += w * v.y;
    }
    acc0 *= di; acc1 *= di;
    float2* ob = (float2*)out;
    if (!LN) {
        float2 o; o.x = acc0; o.y = acc1;
        ob[(size_t)node * 64 + lane] = o;
    } else {
        float v0 = acc0 + bias[2 * lane], v1 = acc1 + bias[2 * lane + 1];
        float s = v0 + v1;
        #pragma unroll
        for (int o = 32; o > 0; o >>= 1) s += __shfl_xor(s, o, 64);
        float mu = s * (1.0f / 128.0f);
        float d0 = v0 - mu, d1 = v1 - mu;
        float q = d0 * d0 + d1 * d1;
        #pragma unroll
        for (int o = 32; o > 0; o >>= 1) q += __shfl_xor(q, o, 64);
        float rstd = rsqrtf(q * (1.0f / 128.0f) + 1e-5f);
        float2 o;
        o.x = d0 * rstd * gamma[2 * lane] + beta[2 * lane];
        o.y = d1 * rstd * gamma[2 * lane + 1] + beta[2 * lane + 1];
        ob[(size_t)node * 64 + lane] = o;
    }
}

// ---------------- fused GEMM1(+bias+relu)+GEMM2, bf16-split MFMA ----------------
// G = relu(A@W1+b1)@W2 ; A:[M,128] fp32, G:[M,128] fp32.
// C = Ah*Bh + Al*Bh + Ah*Bl per tile (drops Al*Bl ~2^-18). One wave = 16 rows.
// h (fp32) round-trips through per-wave LDS as hi/lo bf16 (C-layout -> A-layout).

__global__ __launch_bounds__(256) void fused_gemm_kernel(const float* __restrict__ A,
                                                         const uint16_t* __restrict__ W1h,
                                                         const uint16_t* __restrict__ W1l,
                                                         const float* __restrict__ b1,
                                                         const uint16_t* __restrict__ W2h,
                                                         const uint16_t* __restrict__ W2l,
                                                         float* __restrict__ G, int M) {
    __shared__ __align__(16) uint16_t hh[4 * 16 * RS];
    __shared__ __align__(16) uint16_t hl[4 * 16 * RS];
    int lane = threadIdx.x & 63;
    int wave = threadIdx.x >> 6;
    int m_base = (blockIdx.x * 4 + wave) * 16;
    if (m_base >= M) return;              // M % 16 == 0; no barriers used
    int r15 = lane & 15;
    int quad = lane >> 4;
    int kofs = quad * 8;
    uint16_t* Hh = hh + wave * 16 * RS;
    uint16_t* Hl = hl + wave * 16 * RS;

    // A frags (fp32 -> hi/lo bf16): A[m=r15][k=quad*8+j]
    bf16x8 ah[4], al[4];
    const float* arow = A + (size_t)(m_base + r15) * IN_DIM + kofs;
    #pragma unroll
    for (int ks = 0; ks < 4; ++ks) {
        #pragma unroll
        for (int j = 0; j < 8; ++j) {
            float v = arow[ks * 32 + j];
            uint16_t h = f2bf(v);
            ah[ks][j] = (short)h;
            al[ks][j] = (short)f2bf(v - bf2f(h));
        }
    }
    // phase 1: h = relu(A@W1+b1)  [16 x 256] -> LDS hi/lo
    #pragma unroll
    for (int nt = 0; nt < HID_DIM / 16; ++nt) {
        int ncol = nt * 16 + r15;
        const uint16_t* bh = W1h + (size_t)ncol * IN_DIM + kofs;
        const uint16_t* bl = W1l + (size_t)ncol * IN_DIM + kofs;
        f32x4 acc = {0.f, 0.f, 0.f, 0.f};
        #pragma unroll
        for (int ks = 0; ks < 4; ++ks) {
            bf16x8 bhv = *(const bf16x8*)(bh + ks * 32);
            bf16x8 blv = *(const bf16x8*)(bl + ks * 32);
            acc = __builtin_amdgcn_mfma_f32_16x16x32_bf16(ah[ks], bhv, acc, 0, 0, 0);
            acc = __builtin_amdgcn_mfma_f32_16x16x32_bf16(al[ks], bhv, acc, 0, 0, 0);
            acc = __builtin_amdgcn_mfma_f32_16x16x32_bf16(ah[ks], blv, acc, 0, 0, 0);
        }
        float bv = b1[ncol];
        #pragma unroll
        for (int r = 0; r < 4; ++r) {      // C/D: col=lane&15, row=quad*4+r
            float hval = fmaxf(acc[r] + bv, 0.f);
            uint16_t h = f2bf(hval);
            Hh[(quad * 4 + r) * RS + ncol] = h;
            Hl[(quad * 4 + r) * RS + ncol] = f2bf(hval - bf2f(h));
        }
    }
    // phase 2: g = h@W2  [16 x 128]  (intra-wave LDS dep; compiler inserts waits)
    bf16x8 a2h[8], a2l[8];
    #pragma unroll
    for (int ks = 0; ks < 8; ++ks) {
        a2h[ks] = *(const bf16x8*)(Hh + r15 * RS + kofs + ks * 32);
        a2l[ks] = *(const bf16x8*)(Hl + r15 * RS + kofs + ks * 32);
    }
    #pragma unroll
    for (int nt = 0; nt < OUT_DIM / 16; ++nt) {
        int ncol = nt * 16 + r15;
        const uint16_t* bh = W2h + (size_t)ncol * HID_DIM + kofs;
        const uint16_t* bl = W2l + (size_t)ncol * HID_DIM + kofs;
        f32x4 acc = {0.f, 0.f, 0.f, 0.f};
        #pragma unroll
        for (int ks = 0; ks < 8; ++ks) {
            bf16x8 bhv = *(const bf16x8*)(bh + ks * 32);
            bf16x8 blv = *(const bf16x8*)(bl + ks * 32);
            acc = __builtin_amdgcn_mfma_f32_16x16x32_bf16(a2h[ks], bhv, acc, 0, 0, 0);
            acc = __builtin_amdgcn_mfma_f32_16x16x32_bf16(a2l[ks], bhv, acc, 0, 0, 0);
            acc = __builtin_amdgcn_mfma_f32_16x16x32_bf16(a2h[ks], blv, acc, 0, 0, 0);
        }
        #pragma unroll
        for (int r = 0; r < 4; ++r)
            G[(size_t)(m_base + quad * 4 + r) * OUT_DIM + ncol] = acc[r];
    }
}

// ---------------- launch ----------------

extern "C" void kernel_launch(void* const* d_in, const int* in_sizes, int n_in,
                              void* d_out, int out_size, void* d_ws, size_t ws_size,
                              hipStream_t stream) {
    const float* x     = (const float*)d_in[0];   // fp32 [100000,128]
    const int*   ei    = (const int*)d_in[1];     // int32 or int64 [2,1.6M]
    const float* W1    = (const float*)d_in[2];   // fp32 [128,256]
    const float* b1    = (const float*)d_in[3];   // fp32 [256]
    const float* W2    = (const float*)d_in[4];   // fp32 [256,128]
    const float* b2    = (const float*)d_in[5];   // fp32 [128]
    const float* gamma = (const float*)d_in[6];
    const float* beta  = (const float*)d_in[7];

    char* ws = (char*)d_ws;
    size_t off = 0;
    auto alloc = [&](size_t bytes) -> void* {
        void* p = ws + off;
        off += (bytes + 511) & ~(size_t)511;
        return p;
    };
    int*      cnt     = (int*)alloc((size_t)N_NODES * 4);
    int*      row_ptr = (int*)alloc((size_t)(N_NODES + 1) * 4);
    int*      cursor  = (int*)alloc((size_t)N_NODES * 4);
    float*    dinv    = (float*)alloc((size_t)N_NODES * 4);
    int*      bsum    = (int*)alloc(512 * 4);
    int*      flag    = (int*)alloc(4);
    uint16_t* W1h     = (uint16_t*)alloc((size_t)IN_DIM * HID_DIM * 2);
    uint16_t* W1l     = (uint16_t*)alloc((size_t)IN_DIM * HID_DIM * 2);
    uint16_t* W2h     = (uint16_t*)alloc((size_t)HID_DIM * OUT_DIM * 2);
    uint16_t* W2l     = (uint16_t*)alloc((size_t)HID_DIM * OUT_DIM * 2);
    int*      colv    = (int*)alloc((size_t)N_EDGES * 4);
    float*    g       = (float*)alloc((size_t)N_NODES * OUT_DIM * 4);
    // ~59.7 MB total. Guard: too-small ws leaves d_out zeroed
    // (absmax reads exactly max|ref| -> distinct "ws too small" signature).
    if (ws_size < off) return;

    float* xa = (float*)d_out;   // d_out (51.2 MB fp32) doubles as A_norm@x scratch

    const int EB = (N_EDGES + 255) / 256;
    const int NB = (N_NODES + 255) / 256;
    const int AB = (N_NODES + 3) / 4;      // 1 wave per node
    const int GB = (N_NODES + 63) / 64;    // 16 rows per wave, 4 waves per block

    detect_kernel<<<1, 64, 0, stream>>>(ei, flag);
    hipMemsetAsync(cnt, 0, (size_t)N_NODES * 4, stream);
    count_kernel<<<EB, 256, 0, stream>>>(ei, flag, cnt);
    scan_a<<<NB, 256, 0, stream>>>(cnt, row_ptr, bsum, N_NODES);
    scan_b<<<1, 512, 0, stream>>>(bsum, NB);
    scan_c<<<NB, 256, 0, stream>>>(row_ptr, bsum, N_NODES, N_EDGES);
    finalize_kernel<<<NB, 256, 0, stream>>>(cnt, row_ptr, cursor, dinv);
    fill_kernel<<<EB, 256, 0, stream>>>(ei, flag, cursor, colv);

    wsplit_kernel<<<(IN_DIM * HID_DIM + 255) / 256, 256, 0, stream>>>(W1, W1h, W1l, IN_DIM, HID_DIM);
    wsplit_kernel<<<(HID_DIM * OUT_DIM + 255) / 256, 256, 0, stream>>>(W2, W2h, W2l, HID_DIM, OUT_DIM);

    // xa = A_norm @ x  (aggregate in 128-d input space; xa lives in d_out)
    agg_kernel<false><<<AB, 256, 0, stream>>>(x, row_ptr, colv, dinv,
                                              nullptr, nullptr, nullptr, xa);
    // g = relu(xa@W1+b1)@W2
    fused_gemm_kernel<<<GB, 256, 0, stream>>>(xa, W1h, W1l, b1, W2h, W2l, g, N_NODES);
    // out = LN(A_norm@g + b2)
    agg_kernel<true><<<AB, 256, 0, stream>>>(g, row_ptr, colv, dinv,
                                             b2, gamma, beta, (float*)d_out);
}

// Round 4
// 639.629 us; speedup vs baseline: 1.3300x; 1.3300x over previous
//
#include <hip/hip_runtime.h>
#include <stdint.h>

#define N_NODES 100000
#define N_EDGES 1600000
#define IN_DIM  128
#define HID_DIM 256
#define OUT_DIM 128
#define RS 264   // padded LDS row stride (bf16 elems); 264*2=528 B, 528%16==0

typedef __attribute__((ext_vector_type(8))) short bf16x8;
typedef __attribute__((ext_vector_type(4))) float f32x4;

__device__ __forceinline__ float bf2f(uint16_t h) {
    union { uint32_t u; float f; } c; c.u = ((uint32_t)h) << 16; return c.f;
}
__device__ __forceinline__ uint16_t f2bf(float f) {
    union { float f; uint32_t u; } c; c.f = f;
    uint32_t u = c.u;
    return (uint16_t)((u + 0x7fffu + ((u >> 16) & 1u)) >> 16);  // RNE
}
__device__ __forceinline__ int clampi(int v) {
    v = v < 0 ? 0 : v;
    return v >= N_NODES ? N_NODES - 1 : v;
}

// ---------------- int64-vs-int32 edge_index detection ----------------

__global__ void detect_kernel(const int* __restrict__ ei, int* __restrict__ flag) {
    if (threadIdx.x == 0 && blockIdx.x == 0) {
        int z = 1;
        for (int i = 0; i < 16; ++i)
            if (ei[2 * i + 1] != 0) z = 0;
        flag[0] = z;
    }
}

__device__ __forceinline__ int src_at(const int* ei, int isI64, int e) {
    return clampi(isI64 ? ei[2 * (size_t)e] : ei[e]);
}
__device__ __forceinline__ int dst_at(const int* ei, int isI64, int e) {
    return clampi(isI64 ? ei[2 * (size_t)N_EDGES + 2 * (size_t)e]
                        : ei[(size_t)N_EDGES + e]);
}

// ---------------- CSR construction ----------------

__global__ __launch_bounds__(256) void count_kernel(const int* __restrict__ ei,
                                                    const int* __restrict__ flag,
                                                    int* __restrict__ cnt) {
    int e = blockIdx.x * 256 + threadIdx.x;
    if (e < N_EDGES) atomicAdd(&cnt[dst_at(ei, flag[0], e)], 1);
}

__global__ __launch_bounds__(256) void scan_a(const int* __restrict__ cnt,
                                              int* __restrict__ row_ptr,
                                              int* __restrict__ bsum, int n) {
    __shared__ int lds[256];
    int t = threadIdx.x, g = blockIdx.x * 256 + t;
    int v = (g < n) ? cnt[g] : 0;
    lds[t] = v; __syncthreads();
    for (int off = 1; off < 256; off <<= 1) {
        int x = (t >= off) ? lds[t - off] : 0;
        __syncthreads();
        if (t >= off) lds[t] += x;
        __syncthreads();
    }
    if (g < n) row_ptr[g] = lds[t] - v;     // exclusive
    if (t == 255) bsum[blockIdx.x] = lds[t];
}

__global__ __launch_bounds__(512) void scan_b(int* __restrict__ bsum, int nb) {
    __shared__ int lds[512];
    int t = threadIdx.x;
    int v = (t < nb) ? bsum[t] : 0;
    lds[t] = v; __syncthreads();
    for (int off = 1; off < 512; off <<= 1) {
        int x = (t >= off) ? lds[t - off] : 0;
        __syncthreads();
        if (t >= off) lds[t] += x;
        __syncthreads();
    }
    if (t < nb) bsum[t] = lds[t] - v;       // exclusive
}

__global__ __launch_bounds__(256) void scan_c(int* __restrict__ row_ptr,
                                              const int* __restrict__ bsum,
                                              int n, int total) {
    int g = blockIdx.x * 256 + threadIdx.x;
    if (g < n) row_ptr[g] += bsum[blockIdx.x];
    if (g == 0) row_ptr[n] = total;
}

__global__ __launch_bounds__(256) void finalize_kernel(const int* __restrict__ cnt,
                                                       const int* __restrict__ row_ptr,
                                                       int* __restrict__ cursor,
                                                       float* __restrict__ dinv) {
    int i = blockIdx.x * 256 + threadIdx.x;
    if (i < N_NODES) {
        cursor[i] = row_ptr[i];
        dinv[i] = rsqrtf((float)(cnt[i] + 1));  // +1 self-loop; always > 0
    }
}

__global__ __launch_bounds__(256) void fill_kernel(const int* __restrict__ ei,
                                                   const int* __restrict__ flag,
                                                   int* __restrict__ cursor,
                                                   int* __restrict__ colv) {
    int e = blockIdx.x * 256 + threadIdx.x;
    if (e < N_EDGES) {
        int isI64 = flag[0];
        int slot = atomicAdd(&cursor[dst_at(ei, isI64, e)], 1);
        colv[slot] = src_at(ei, isI64, e);
    }
}

// ---------------- weight transpose + hi/lo bf16 split ----------------

__global__ __launch_bounds__(256) void wsplit_kernel(const float* __restrict__ W,
                                                     uint16_t* __restrict__ Wh,
                                                     uint16_t* __restrict__ Wl,
                                                     int K, int N) {
    int idx = blockIdx.x * 256 + threadIdx.x;
    if (idx < K * N) {
        int k = idx / N, n = idx - k * N;
        float v = W[idx];
        uint16_t h = f2bf(v);
        Wh[n * K + k] = h;
        Wl[n * K + k] = f2bf(v - bf2f(h));
    }
}

// ---------------- normalized aggregation (128-dim fp32 rows) ----------------
// 2 nodes/wave: lanes 0-31 node A, 32-63 node B; float4/lane = 512B row.
// Unroll-2 software pipeline: 2 independent gathers in flight.

template<bool LN>
__global__ __launch_bounds__(256) void agg_kernel(const float* __restrict__ feat,
                                                  const int* __restrict__ row_ptr,
                                                  const int* __restrict__ colv,
                                                  const float* __restrict__ dinv,
                                                  const float* __restrict__ bias,
                                                  const float* __restrict__ gamma,
                                                  const float* __restrict__ beta,
                                                  float* __restrict__ out) {
    int node = blockIdx.x * 8 + (threadIdx.x >> 5);
    if (node >= N_NODES) return;
    int lane = threadIdx.x & 31;
    const float4* base = (const float4*)feat;
    float di = dinv[node];
    float4 u = base[(size_t)node * 32 + lane];
    float a0 = di * u.x, a1 = di * u.y, a2 = di * u.z, a3 = di * u.w;
    int e = row_ptr[node], e1 = row_ptr[node + 1];
    int sa = (e < e1) ? colv[e] : 0;
    int sb = (e + 1 < e1) ? colv[e + 1] : 0;
    while (e + 2 <= e1) {
        sa = clampi(sa); sb = clampi(sb);
        float wa = dinv[sa], wb = dinv[sb];
        float4 va = base[(size_t)sa * 32 + lane];
        float4 vb = base[(size_t)sb * 32 + lane];
        int na = (e + 2 < e1) ? colv[e + 2] : 0;
        int nb = (e + 3 < e1) ? colv[e + 3] : 0;
        a0 += wa * va.x; a1 += wa * va.y; a2 += wa * va.z; a3 += wa * va.w;
        a0 += wb * vb.x; a1 += wb * vb.y; a2 += wb * vb.z; a3 += wb * vb.w;
        sa = na; sb = nb;
        e += 2;
    }
    if (e < e1) {
        sa = clampi(sa);
        float w = dinv[sa];
        float4 v = base[(size_t)sa * 32 + lane];
        a0 += w * v.x; a1 += w * v.y; a2 += w * v.z; a3 += w * v.w;
    }
    a0 *= di; a1 *= di; a2 *= di; a3 *= di;
    float4* ob = (float4*)out;
    if (!LN) {
        float4 o; o.x = a0; o.y = a1; o.z = a2; o.w = a3;
        ob[(size_t)node * 32 + lane] = o;
    } else {
        const float4* b4 = (const float4*)bias;
        float4 bb = b4[lane];
        float v0 = a0 + bb.x, v1 = a1 + bb.y, v2 = a2 + bb.z, v3 = a3 + bb.w;
        float s = v0 + v1 + v2 + v3;
        #pragma unroll
        for (int o = 16; o > 0; o >>= 1) s += __shfl_xor(s, o, 64);  // 32-lane group
        float mu = s * (1.0f / 128.0f);
        float d0 = v0 - mu, d1 = v1 - mu, d2 = v2 - mu, d3 = v3 - mu;
        float q = d0 * d0 + d1 * d1 + d2 * d2 + d3 * d3;
        #pragma unroll
        for (int o = 16; o > 0; o >>= 1) q += __shfl_xor(q, o, 64);
        float rstd = rsqrtf(q * (1.0f / 128.0f) + 1e-5f);
        const float4* g4 = (const float4*)gamma;
        const float4* be4 = (const float4*)beta;
        float4 gg = g4[lane], bt = be4[lane];
        float4 o;
        o.x = d0 * rstd * gg.x + bt.x;
        o.y = d1 * rstd * gg.y + bt.y;
        o.z = d2 * rstd * gg.z + bt.z;
        o.w = d3 * rstd * gg.w + bt.w;
        ob[(size_t)node * 32 + lane] = o;
    }
}

// ---------------- fused GEMM1(+bias+relu)+GEMM2, bf16-split MFMA ----------------
// Block = 64 rows, 4 waves. Phase 1: wave w computes h cols [w*64, w*64+64)
// for all 64 rows (4 m-tiles, B-frag reused across 4 acc chains -> 4x ILP,
// 4x less weight traffic). h (hi/lo bf16) in block-shared LDS. Phase 2: wave w
// computes G cols [w*32, w*32+32), W2 frags held in regs, h streamed via
// ds_read_b128. C = Ah*Bh + Al*Bh + Ah*Bl (drops Al*Bl ~2^-18).

__global__ __launch_bounds__(256) void fused_gemm_kernel(const float* __restrict__ A,
                                                         const uint16_t* __restrict__ W1h,
                                                         const uint16_t* __restrict__ W1l,
                                                         const float* __restrict__ b1,
                                                         const uint16_t* __restrict__ W2h,
                                                         const uint16_t* __restrict__ W2l,
                                                         float* __restrict__ G, int M) {
    __shared__ __align__(16) uint16_t Hh[64 * RS];   // 33792 B
    __shared__ __align__(16) uint16_t Hl[64 * RS];   // 33792 B
    int lane = threadIdx.x & 63;
    int wave = threadIdx.x >> 6;
    int r15 = lane & 15;
    int quad = lane >> 4;
    int kofs = quad * 8;
    int blk_row = blockIdx.x * 64;

    // A-frags for 4 m-tiles: A[m=r15][k=quad*8+j], fp32 -> hi/lo bf16
    bf16x8 ah[4][4], al[4][4];
    #pragma unroll
    for (int mt = 0; mt < 4; ++mt) {
        bool valid = (blk_row + mt * 16) < M;        // M%16==0: whole tile valid or not
        int row = valid ? (blk_row + mt * 16 + r15) : 0;
        const float* arow = A + (size_t)row * IN_DIM + kofs;
        #pragma unroll
        for (int ks = 0; ks < 4; ++ks) {
            float4 v0 = *(const float4*)(arow + ks * 32);
            float4 v1 = *(const float4*)(arow + ks * 32 + 4);
            float vv[8] = {v0.x, v0.y, v0.z, v0.w, v1.x, v1.y, v1.z, v1.w};
            #pragma unroll
            for (int j = 0; j < 8; ++j) {
                uint16_t h = f2bf(vv[j]);
                ah[mt][ks][j] = (short)h;
                al[mt][ks][j] = (short)f2bf(vv[j] - bf2f(h));
            }
        }
    }

    // phase 1: h = relu(A@W1+b1), wave's 4 nt-tiles (64 cols)
    #pragma unroll
    for (int nt = 0; nt < 4; ++nt) {
        int ncol = (wave * 4 + nt) * 16 + r15;       // 0..255
        const uint16_t* bh = W1h + (size_t)ncol * IN_DIM + kofs;
        const uint16_t* bl = W1l + (size_t)ncol * IN_DIM + kofs;
        f32x4 acc[4];
        #pragma unroll
        for (int mt = 0; mt < 4; ++mt) acc[mt] = (f32x4){0.f, 0.f, 0.f, 0.f};
        #pragma unroll
        for (int ks = 0; ks < 4; ++ks) {
            bf16x8 bhv = *(const bf16x8*)(bh + ks * 32);
            bf16x8 blv = *(const bf16x8*)(bl + ks * 32);
            #pragma unroll
            for (int mt = 0; mt < 4; ++mt) {
                acc[mt] = __builtin_amdgcn_mfma_f32_16x16x32_bf16(ah[mt][ks], bhv, acc[mt], 0, 0, 0);
                acc[mt] = __builtin_amdgcn_mfma_f32_16x16x32_bf16(al[mt][ks], bhv, acc[mt], 0, 0, 0);
                acc[mt] = __builtin_amdgcn_mfma_f32_16x16x32_bf16(ah[mt][ks], blv, acc[mt], 0, 0, 0);
            }
        }
        float bv = b1[ncol];
        #pragma unroll
        for (int mt = 0; mt < 4; ++mt) {
            #pragma unroll
            for (int r = 0; r < 4; ++r) {            // C/D: col=lane&15, row=quad*4+r
                float hval = fmaxf(acc[mt][r] + bv, 0.f);
                uint16_t h = f2bf(hval);
                int lrow = mt * 16 + quad * 4 + r;
                Hh[lrow * RS + ncol] = h;
                Hl[lrow * RS + ncol] = f2bf(hval - bf2f(h));
            }
        }
    }
    __syncthreads();

    // phase 2: G = h@W2, wave's 2 nt-tiles (32 cols), all 4 m-tiles
    #pragma unroll
    for (int nt = 0; nt < 2; ++nt) {
        int ncol = (wave * 2 + nt) * 16 + r15;       // 0..127
        const uint16_t* bh = W2h + (size_t)ncol * HID_DIM + kofs;
        const uint16_t* bl = W2l + (size_t)ncol * HID_DIM + kofs;
        bf16x8 b2h[8], b2l[8];
        #pragma unroll
        for (int ks = 0; ks < 8; ++ks) {
            b2h[ks] = *(const bf16x8*)(bh + ks * 32);
            b2l[ks] = *(const bf16x8*)(bl + ks * 32);
        }
        f32x4 acc[4];
        #pragma unroll
        for (int mt = 0; mt < 4; ++mt) acc[mt] = (f32x4){0.f, 0.f, 0.f, 0.f};
        #pragma unroll
        for (int ks = 0; ks < 8; ++ks) {
            #pragma unroll
            for (int mt = 0; mt < 4; ++mt) {
                bf16x8 a2h = *(const bf16x8*)(Hh + (mt * 16 + r15) * RS + ks * 32 + kofs);
                bf16x8 a2l = *(const bf16x8*)(Hl + (mt * 16 + r15) * RS + ks * 32 + kofs);
                acc[mt] = __builtin_amdgcn_mfma_f32_16x16x32_bf16(a2h, b2h[ks], acc[mt], 0, 0, 0);
                acc[mt] = __builtin_amdgcn_mfma_f32_16x16x32_bf16(a2l, b2h[ks], acc[mt], 0, 0, 0);
                acc[mt] = __builtin_amdgcn_mfma_f32_16x16x32_bf16(a2h, b2l[ks], acc[mt], 0, 0, 0);
            }
        }
        #pragma unroll
        for (int mt = 0; mt < 4; ++mt) {
            if ((blk_row + mt * 16) < M) {
                #pragma unroll
                for (int r = 0; r < 4; ++r)
                    G[(size_t)(blk_row + mt * 16 + quad * 4 + r) * OUT_DIM + ncol] = acc[mt][r];
            }
        }
    }
}

// ---------------- launch ----------------

extern "C" void kernel_launch(void* const* d_in, const int* in_sizes, int n_in,
                              void* d_out, int out_size, void* d_ws, size_t ws_size,
                              hipStream_t stream) {
    const float* x     = (const float*)d_in[0];   // fp32 [100000,128]
    const int*   ei    = (const int*)d_in[1];     // int32 or int64 [2,1.6M]
    const float* W1    = (const float*)d_in[2];   // fp32 [128,256]
    const float* b1    = (const float*)d_in[3];   // fp32 [256]
    const float* W2    = (const float*)d_in[4];   // fp32 [256,128]
    const float* b2    = (const float*)d_in[5];   // fp32 [128]
    const float* gamma = (const float*)d_in[6];
    const float* beta  = (const float*)d_in[7];

    char* ws = (char*)d_ws;
    size_t off = 0;
    auto alloc = [&](size_t bytes) -> void* {
        void* p = ws + off;
        off += (bytes + 511) & ~(size_t)511;
        return p;
    };
    int*      cnt     = (int*)alloc((size_t)N_NODES * 4);
    int*      row_ptr = (int*)alloc((size_t)(N_NODES + 1) * 4);
    int*      cursor  = (int*)alloc((size_t)N_NODES * 4);
    float*    dinv    = (float*)alloc((size_t)N_NODES * 4);
    int*      bsum    = (int*)alloc(512 * 4);
    int*      flag    = (int*)alloc(4);
    uint16_t* W1h     = (uint16_t*)alloc((size_t)IN_DIM * HID_DIM * 2);
    uint16_t* W1l     = (uint16_t*)alloc((size_t)IN_DIM * HID_DIM * 2);
    uint16_t* W2h     = (uint16_t*)alloc((size_t)HID_DIM * OUT_DIM * 2);
    uint16_t* W2l     = (uint16_t*)alloc((size_t)HID_DIM * OUT_DIM * 2);
    int*      colv    = (int*)alloc((size_t)N_EDGES * 4);
    float*    g       = (float*)alloc((size_t)N_NODES * OUT_DIM * 4);
    if (ws_size < off) return;   // "ws too small" signature: absmax == max|ref|

    float* xa = (float*)d_out;   // d_out (51.2 MB fp32) doubles as A_norm@x scratch

    const int EB = (N_EDGES + 255) / 256;
    const int NB = (N_NODES + 255) / 256;
    const int AB = (N_NODES + 7) / 8;      // 8 nodes per block (2 per wave)
    const int GB = (N_NODES + 63) / 64;    // 64 rows per block

    detect_kernel<<<1, 64, 0, stream>>>(ei, flag);
    hipMemsetAsync(cnt, 0, (size_t)N_NODES * 4, stream);
    count_kernel<<<EB, 256, 0, stream>>>(ei, flag, cnt);
    scan_a<<<NB, 256, 0, stream>>>(cnt, row_ptr, bsum, N_NODES);
    scan_b<<<1, 512, 0, stream>>>(bsum, NB);
    scan_c<<<NB, 256, 0, stream>>>(row_ptr, bsum, N_NODES, N_EDGES);
    finalize_kernel<<<NB, 256, 0, stream>>>(cnt, row_ptr, cursor, dinv);
    fill_kernel<<<EB, 256, 0, stream>>>(ei, flag, cursor, colv);

    wsplit_kernel<<<(IN_DIM * HID_DIM + 255) / 256, 256, 0, stream>>>(W1, W1h, W1l, IN_DIM, HID_DIM);
    wsplit_kernel<<<(HID_DIM * OUT_DIM + 255) / 256, 256, 0, stream>>>(W2, W2h, W2l, HID_DIM, OUT_DIM);

    // xa = A_norm @ x  (aggregate in 128-d input space; xa lives in d_out)
    agg_kernel<false><<<AB, 256, 0, stream>>>(x, row_ptr, colv, dinv,
                                              nullptr, nullptr, nullptr, xa);
    // g = relu(xa@W1+b1)@W2
    fused_gemm_kernel<<<GB, 256, 0, stream>>>(xa, W1h, W1l, b1, W2h, W2l, g, N_NODES);
    // out = LN(A_norm@g + b2)
    agg_kernel<true><<<AB, 256, 0, stream>>>(g, row_ptr, colv, dinv,
                                             b2, gamma, beta, (float*)d_out);
}

// Round 5
// 449.390 us; speedup vs baseline: 1.8930x; 1.4233x over previous
//
#include <hip/hip_runtime.h>
#include <hip/hip_fp16.h>
#include <stdint.h>

#define N_NODES 100000
#define N_EDGES 1600000
#define IN_DIM  128
#define HID_DIM 256
#define OUT_DIM 128
#define RS 264   // padded LDS row stride (bf16 elems)

typedef __attribute__((ext_vector_type(8))) short bf16x8;
typedef __attribute__((ext_vector_type(4))) float f32x4;

__device__ __forceinline__ float bf2f(uint16_t h) {
    union { uint32_t u; float f; } c; c.u = ((uint32_t)h) << 16; return c.f;
}
__device__ __forceinline__ uint16_t f2bf(float f) {
    union { float f; uint32_t u; } c; c.f = f;
    uint32_t u = c.u;
    return (uint16_t)((u + 0x7fffu + ((u >> 16) & 1u)) >> 16);  // RNE
}
__device__ __forceinline__ int clampi(int v) {
    v = v < 0 ? 0 : v;
    return v >= N_NODES ? N_NODES - 1 : v;
}
__device__ __forceinline__ float2 h2f2(uint32_t u) {
    union { uint32_t u; __half2 h; } c; c.u = u;
    return __half22float2(c.h);
}
__device__ __forceinline__ uint32_t packh(float a, float b) {
    union { __half2 h; uint32_t u; } c; c.h = __floats2half2_rn(a, b);
    return c.u;
}
__device__ __forceinline__ uint16_t f2h(float a) {
    union { __half h; uint16_t s; } c; c.h = __float2half_rn(a);
    return c.s;
}

// ---------------- int64-vs-int32 edge_index detection ----------------

__global__ void detect_kernel(const int* __restrict__ ei, int* __restrict__ flag) {
    if (threadIdx.x == 0 && blockIdx.x == 0) {
        int z = 1;
        for (int i = 0; i < 16; ++i)
            if (ei[2 * i + 1] != 0) z = 0;
        flag[0] = z;
    }
}

__device__ __forceinline__ int src_at(const int* ei, int isI64, int e) {
    return clampi(isI64 ? ei[2 * (size_t)e] : ei[e]);
}
__device__ __forceinline__ int dst_at(const int* ei, int isI64, int e) {
    return clampi(isI64 ? ei[2 * (size_t)N_EDGES + 2 * (size_t)e]
                        : ei[(size_t)N_EDGES + e]);
}

// ---------------- CSR construction ----------------
// count: histogram + per-edge slot index (coalesced write) -> fill needs no atomics.

__global__ __launch_bounds__(256) void count_kernel(const int* __restrict__ ei,
                                                    const int* __restrict__ flag,
                                                    int* __restrict__ cnt,
                                                    int* __restrict__ slot) {
    int e = blockIdx.x * 256 + threadIdx.x;
    if (e < N_EDGES) slot[e] = atomicAdd(&cnt[dst_at(ei, flag[0], e)], 1);
}

__global__ __launch_bounds__(256) void scan_a(const int* __restrict__ cnt,
                                              int* __restrict__ row_ptr,
                                              int* __restrict__ bsum, int n) {
    __shared__ int lds[256];
    int t = threadIdx.x, g = blockIdx.x * 256 + t;
    int v = (g < n) ? cnt[g] : 0;
    lds[t] = v; __syncthreads();
    for (int off = 1; off < 256; off <<= 1) {
        int x = (t >= off) ? lds[t - off] : 0;
        __syncthreads();
        if (t >= off) lds[t] += x;
        __syncthreads();
    }
    if (g < n) row_ptr[g] = lds[t] - v;     // exclusive
    if (t == 255) bsum[blockIdx.x] = lds[t];
}

__global__ __launch_bounds__(512) void scan_b(int* __restrict__ bsum, int nb) {
    __shared__ int lds[512];
    int t = threadIdx.x;
    int v = (t < nb) ? bsum[t] : 0;
    lds[t] = v; __syncthreads();
    for (int off = 1; off < 512; off <<= 1) {
        int x = (t >= off) ? lds[t - off] : 0;
        __syncthreads();
        if (t >= off) lds[t] += x;
        __syncthreads();
    }
    if (t < nb) bsum[t] = lds[t] - v;       // exclusive
}

__global__ __launch_bounds__(256) void scan_c(int* __restrict__ row_ptr,
                                              const int* __restrict__ bsum,
                                              int n, int total) {
    int g = blockIdx.x * 256 + threadIdx.x;
    if (g < n) row_ptr[g] += bsum[blockIdx.x];
    if (g == 0) row_ptr[n] = total;
}

__global__ __launch_bounds__(256) void finalize_kernel(const int* __restrict__ cnt,
                                                       float* __restrict__ dinv) {
    int i = blockIdx.x * 256 + threadIdx.x;
    if (i < N_NODES) dinv[i] = rsqrtf((float)(cnt[i] + 1));  // +1 self-loop
}

__global__ __launch_bounds__(256) void fill_kernel(const int* __restrict__ ei,
                                                   const int* __restrict__ flag,
                                                   const int* __restrict__ row_ptr,
                                                   const int* __restrict__ slot,
                                                   int* __restrict__ colv) {
    int e = blockIdx.x * 256 + threadIdx.x;
    if (e < N_EDGES) {
        int isI64 = flag[0];
        int d = dst_at(ei, isI64, e);
        colv[row_ptr[d] + slot[e]] = src_at(ei, isI64, e);   // no atomic
    }
}

// ---------------- weight transpose + hi/lo bf16 split ----------------

__global__ __launch_bounds__(256) void wsplit_kernel(const float* __restrict__ W,
                                                     uint16_t* __restrict__ Wh,
                                                     uint16_t* __restrict__ Wl,
                                                     int K, int N) {
    int idx = blockIdx.x * 256 + threadIdx.x;
    if (idx < K * N) {
        int k = idx / N, n = idx - k * N;
        float v = W[idx];
        uint16_t h = f2bf(v);
        Wh[n * K + k] = h;
        Wl[n * K + k] = f2bf(v - bf2f(h));
    }
}

// ---------------- x -> fp16 rows pre-scaled by dinv ----------------
// xs16[i][j] = fp16(dinv[i] * x[i][j]); 256 B per row.

__global__ __launch_bounds__(256) void xscale_kernel(const float* __restrict__ x,
                                                     const float* __restrict__ dinv,
                                                     uint32_t* __restrict__ xs16) {
    int idx = blockIdx.x * 256 + threadIdx.x;          // one float4 -> one uint2
    if (idx < N_NODES * 32) {
        float d = dinv[idx >> 5];
        float4 v = ((const float4*)x)[idx];
        uint2 o;
        o.x = packh(d * v.x, d * v.y);
        o.y = packh(d * v.z, d * v.w);
        ((uint2*)xs16)[idx] = o;
    }
}

// ---------------- normalized aggregation over fp16 pre-scaled rows ----------------
// rows[s] = dinv[s]*feat[s] (fp16). out[i] = dinv[i]*(sum_edges rows[s] + rows[i]).
// 4 nodes/wave: 16 lanes x uint4(16B) = 256B row. Unroll-2 gather pipeline.

template<bool LN>
__global__ __launch_bounds__(256) void agg_kernel(const uint4* __restrict__ rows,
                                                  const int* __restrict__ row_ptr,
                                                  const int* __restrict__ colv,
                                                  const float* __restrict__ dinv,
                                                  const float* __restrict__ bias,
                                                  const float* __restrict__ gamma,
                                                  const float* __restrict__ beta,
                                                  float* __restrict__ out) {
    int node = blockIdx.x * 16 + (threadIdx.x >> 4);
    if (node >= N_NODES) return;
    int l = threadIdx.x & 15;
    float di = dinv[node];
    float acc[8];
    {
        uint4 u = rows[(size_t)node * 16 + l];
        float2 f0 = h2f2(u.x), f1 = h2f2(u.y), f2 = h2f2(u.z), f3 = h2f2(u.w);
        acc[0] = f0.x; acc[1] = f0.y; acc[2] = f1.x; acc[3] = f1.y;
        acc[4] = f2.x; acc[5] = f2.y; acc[6] = f3.x; acc[7] = f3.y;
    }
    int e = row_ptr[node], e1 = row_ptr[node + 1];
    int sa = (e < e1) ? colv[e] : 0;
    int sb = (e + 1 < e1) ? colv[e + 1] : 0;
    while (e + 2 <= e1) {
        uint4 va = rows[(size_t)clampi(sa) * 16 + l];
        uint4 vb = rows[(size_t)clampi(sb) * 16 + l];
        int na = (e + 2 < e1) ? colv[e + 2] : 0;
        int nb = (e + 3 < e1) ? colv[e + 3] : 0;
        {
            float2 f0 = h2f2(va.x), f1 = h2f2(va.y), f2 = h2f2(va.z), f3 = h2f2(va.w);
            acc[0] += f0.x; acc[1] += f0.y; acc[2] += f1.x; acc[3] += f1.y;
            acc[4] += f2.x; acc[5] += f2.y; acc[6] += f3.x; acc[7] += f3.y;
        }
        {
            float2 f0 = h2f2(vb.x), f1 = h2f2(vb.y), f2 = h2f2(vb.z), f3 = h2f2(vb.w);
            acc[0] += f0.x; acc[1] += f0.y; acc[2] += f1.x; acc[3] += f1.y;
            acc[4] += f2.x; acc[5] += f2.y; acc[6] += f3.x; acc[7] += f3.y;
        }
        sa = na; sb = nb; e += 2;
    }
    if (e < e1) {
        uint4 v = rows[(size_t)clampi(sa) * 16 + l];
        float2 f0 = h2f2(v.x), f1 = h2f2(v.y), f2 = h2f2(v.z), f3 = h2f2(v.w);
        acc[0] += f0.x; acc[1] += f0.y; acc[2] += f1.x; acc[3] += f1.y;
        acc[4] += f2.x; acc[5] += f2.y; acc[6] += f3.x; acc[7] += f3.y;
    }
    float* orow = out + (size_t)node * 128 + l * 8;
    if (!LN) {
        float4 o0, o1;
        o0.x = acc[0] * di; o0.y = acc[1] * di; o0.z = acc[2] * di; o0.w = acc[3] * di;
        o1.x = acc[4] * di; o1.y = acc[5] * di; o1.z = acc[6] * di; o1.w = acc[7] * di;
        *(float4*)orow = o0; *(float4*)(orow + 4) = o1;
    } else {
        const float4* b4 = (const float4*)(bias + l * 8);
        float4 bb0 = b4[0], bb1 = b4[1];
        float v[8];
        v[0] = acc[0] * di + bb0.x; v[1] = acc[1] * di + bb0.y;
        v[2] = acc[2] * di + bb0.z; v[3] = acc[3] * di + bb0.w;
        v[4] = acc[4] * di + bb1.x; v[5] = acc[5] * di + bb1.y;
        v[6] = acc[6] * di + bb1.z; v[7] = acc[7] * di + bb1.w;
        float s = 0.f;
        #pragma unroll
        for (int j = 0; j < 8; ++j) s += v[j];
        #pragma unroll
        for (int o = 8; o > 0; o >>= 1) s += __shfl_xor(s, o, 64);   // within 16-lane group
        float mu = s * (1.0f / 128.0f);
        float q = 0.f;
        #pragma unroll
        for (int j = 0; j < 8; ++j) { v[j] -= mu; q += v[j] * v[j]; }
        #pragma unroll
        for (int o = 8; o > 0; o >>= 1) q += __shfl_xor(q, o, 64);
        float rstd = rsqrtf(q * (1.0f / 128.0f) + 1e-5f);
        const float4* g4 = (const float4*)(gamma + l * 8);
        const float4* t4 = (const float4*)(beta + l * 8);
        float4 g0 = g4[0], g1 = g4[1], t0 = t4[0], t1 = t4[1];
        float4 o0, o1;
        o0.x = v[0] * rstd * g0.x + t0.x; o0.y = v[1] * rstd * g0.y + t0.y;
        o0.z = v[2] * rstd * g0.z + t0.z; o0.w = v[3] * rstd * g0.w + t0.w;
        o1.x = v[4] * rstd * g1.x + t1.x; o1.y = v[5] * rstd * g1.y + t1.y;
        o1.z = v[6] * rstd * g1.z + t1.z; o1.w = v[7] * rstd * g1.w + t1.w;
        *(float4*)orow = o0; *(float4*)(orow + 4) = o1;
    }
}

// ---------------- fused GEMM1(+bias+relu)+GEMM2, bf16-split MFMA ----------------
// G16[row] = fp16(dinv[row] * (relu(A@W1+b1)@W2)[row])  -- pre-scaled for agg2.

__global__ __launch_bounds__(256) void fused_gemm_kernel(const float* __restrict__ A,
                                                         const uint16_t* __restrict__ W1h,
                                                         const uint16_t* __restrict__ W1l,
                                                         const float* __restrict__ b1,
                                                         const uint16_t* __restrict__ W2h,
                                                         const uint16_t* __restrict__ W2l,
                                                         const float* __restrict__ dinv,
                                                         uint16_t* __restrict__ G16, int M) {
    __shared__ __align__(16) uint16_t Hh[64 * RS];
    __shared__ __align__(16) uint16_t Hl[64 * RS];
    int lane = threadIdx.x & 63;
    int wave = threadIdx.x >> 6;
    int r15 = lane & 15;
    int quad = lane >> 4;
    int kofs = quad * 8;
    int blk_row = blockIdx.x * 64;

    bf16x8 ah[4][4], al[4][4];
    #pragma unroll
    for (int mt = 0; mt < 4; ++mt) {
        bool valid = (blk_row + mt * 16) < M;
        int row = valid ? (blk_row + mt * 16 + r15) : 0;
        const float* arow = A + (size_t)row * IN_DIM + kofs;
        #pragma unroll
        for (int ks = 0; ks < 4; ++ks) {
            float4 v0 = *(const float4*)(arow + ks * 32);
            float4 v1 = *(const float4*)(arow + ks * 32 + 4);
            float vv[8] = {v0.x, v0.y, v0.z, v0.w, v1.x, v1.y, v1.z, v1.w};
            #pragma unroll
            for (int j = 0; j < 8; ++j) {
                uint16_t h = f2bf(vv[j]);
                ah[mt][ks][j] = (short)h;
                al[mt][ks][j] = (short)f2bf(vv[j] - bf2f(h));
            }
        }
    }

    #pragma unroll
    for (int nt = 0; nt < 4; ++nt) {
        int ncol = (wave * 4 + nt) * 16 + r15;
        const uint16_t* bh = W1h + (size_t)ncol * IN_DIM + kofs;
        const uint16_t* bl = W1l + (size_t)ncol * IN_DIM + kofs;
        f32x4 acc[4];
        #pragma unroll
        for (int mt = 0; mt < 4; ++mt) acc[mt] = (f32x4){0.f, 0.f, 0.f, 0.f};
        #pragma unroll
        for (int ks = 0; ks < 4; ++ks) {
            bf16x8 bhv = *(const bf16x8*)(bh + ks * 32);
            bf16x8 blv = *(const bf16x8*)(bl + ks * 32);
            #pragma unroll
            for (int mt = 0; mt < 4; ++mt) {
                acc[mt] = __builtin_amdgcn_mfma_f32_16x16x32_bf16(ah[mt][ks], bhv, acc[mt], 0, 0, 0);
                acc[mt] = __builtin_amdgcn_mfma_f32_16x16x32_bf16(al[mt][ks], bhv, acc[mt], 0, 0, 0);
                acc[mt] = __builtin_amdgcn_mfma_f32_16x16x32_bf16(ah[mt][ks], blv, acc[mt], 0, 0, 0);
            }
        }
        float bv = b1[ncol];
        #pragma unroll
        for (int mt = 0; mt < 4; ++mt) {
            #pragma unroll
            for (int r = 0; r < 4; ++r) {
                float hval = fmaxf(acc[mt][r] + bv, 0.f);
                uint16_t h = f2bf(hval);
                int lrow = mt * 16 + quad * 4 + r;
                Hh[lrow * RS + ncol] = h;
                Hl[lrow * RS + ncol] = f2bf(hval - bf2f(h));
            }
        }
    }
    __syncthreads();

    #pragma unroll
    for (int nt = 0; nt < 2; ++nt) {
        int ncol = (wave * 2 + nt) * 16 + r15;
        const uint16_t* bh = W2h + (size_t)ncol * HID_DIM + kofs;
        const uint16_t* bl = W2l + (size_t)ncol * HID_DIM + kofs;
        bf16x8 b2h[8], b2l[8];
        #pragma unroll
        for (int ks = 0; ks < 8; ++ks) {
            b2h[ks] = *(const bf16x8*)(bh + ks * 32);
            b2l[ks] = *(const bf16x8*)(bl + ks * 32);
        }
        f32x4 acc[4];
        #pragma unroll
        for (int mt = 0; mt < 4; ++mt) acc[mt] = (f32x4){0.f, 0.f, 0.f, 0.f};
        #pragma unroll
        for (int ks = 0; ks < 8; ++ks) {
            #pragma unroll
            for (int mt = 0; mt < 4; ++mt) {
                bf16x8 a2h = *(const bf16x8*)(Hh + (mt * 16 + r15) * RS + ks * 32 + kofs);
                bf16x8 a2l = *(const bf16x8*)(Hl + (mt * 16 + r15) * RS + ks * 32 + kofs);
                acc[mt] = __builtin_amdgcn_mfma_f32_16x16x32_bf16(a2h, b2h[ks], acc[mt], 0, 0, 0);
                acc[mt] = __builtin_amdgcn_mfma_f32_16x16x32_bf16(a2l, b2h[ks], acc[mt], 0, 0, 0);
                acc[mt] = __builtin_amdgcn_mfma_f32_16x16x32_bf16(a2h, b2l[ks], acc[mt], 0, 0, 0);
            }
        }
        #pragma unroll
        for (int mt = 0; mt < 4; ++mt) {
            if ((blk_row + mt * 16) < M) {
                #pragma unroll
                for (int r = 0; r < 4; ++r) {
                    int row = blk_row + mt * 16 + quad * 4 + r;
                    float dv = dinv[row];
                    G16[(size_t)row * OUT_DIM + ncol] = f2h(dv * acc[mt][r]);
                }
            }
        }
    }
}

// ---------------- launch ----------------

extern "C" void kernel_launch(void* const* d_in, const int* in_sizes, int n_in,
                              void* d_out, int out_size, void* d_ws, size_t ws_size,
                              hipStream_t stream) {
    const float* x     = (const float*)d_in[0];   // fp32 [100000,128]
    const int*   ei    = (const int*)d_in[1];     // int32 or int64 [2,1.6M]
    const float* W1    = (const float*)d_in[2];
    const float* b1    = (const float*)d_in[3];
    const float* W2    = (const float*)d_in[4];
    const float* b2    = (const float*)d_in[5];
    const float* gamma = (const float*)d_in[6];
    const float* beta  = (const float*)d_in[7];

    char* ws = (char*)d_ws;
    size_t off = 0;
    auto alloc = [&](size_t bytes) -> void* {
        void* p = ws + off;
        off += (bytes + 511) & ~(size_t)511;
        return p;
    };
    int*      cnt     = (int*)alloc((size_t)N_NODES * 4);
    int*      row_ptr = (int*)alloc((size_t)(N_NODES + 1) * 4);
    float*    dinv    = (float*)alloc((size_t)N_NODES * 4);
    int*      bsum    = (int*)alloc(512 * 4);
    int*      flag    = (int*)alloc(4);
    uint16_t* W1h     = (uint16_t*)alloc((size_t)IN_DIM * HID_DIM * 2);
    uint16_t* W1l     = (uint16_t*)alloc((size_t)IN_DIM * HID_DIM * 2);
    uint16_t* W2h     = (uint16_t*)alloc((size_t)HID_DIM * OUT_DIM * 2);
    uint16_t* W2l     = (uint16_t*)alloc((size_t)HID_DIM * OUT_DIM * 2);
    int*      colv    = (int*)alloc((size_t)N_EDGES * 4);
    // big region: slot (6.4MB, dead after fill) aliased with xs16/g16 (25.6MB)
    void*     big     = alloc((size_t)N_NODES * IN_DIM * 2);
    int*      slot    = (int*)big;
    uint32_t* xs16    = (uint32_t*)big;       // fp16 rows, written after fill
    uint16_t* g16     = (uint16_t*)big;       // fp16 rows, written after agg1/gemm
    if (ws_size < off) return;   // "ws too small" signature: absmax == max|ref|
    // total ~34 MB

    float* xa = (float*)d_out;   // d_out (51.2 MB fp32) doubles as A_norm@x scratch

    const int EB = (N_EDGES + 255) / 256;
    const int NB = (N_NODES + 255) / 256;
    const int AB = (N_NODES + 15) / 16;    // 16 nodes/block (4 per wave)
    const int GB = (N_NODES + 63) / 64;

    detect_kernel<<<1, 64, 0, stream>>>(ei, flag);
    hipMemsetAsync(cnt, 0, (size_t)N_NODES * 4, stream);
    count_kernel<<<EB, 256, 0, stream>>>(ei, flag, cnt, slot);
    scan_a<<<NB, 256, 0, stream>>>(cnt, row_ptr, bsum, N_NODES);
    scan_b<<<1, 512, 0, stream>>>(bsum, NB);
    scan_c<<<NB, 256, 0, stream>>>(row_ptr, bsum, N_NODES, N_EDGES);
    finalize_kernel<<<NB, 256, 0, stream>>>(cnt, dinv);
    fill_kernel<<<EB, 256, 0, stream>>>(ei, flag, row_ptr, slot, colv);

    wsplit_kernel<<<(IN_DIM * HID_DIM + 255) / 256, 256, 0, stream>>>(W1, W1h, W1l, IN_DIM, HID_DIM);
    wsplit_kernel<<<(HID_DIM * OUT_DIM + 255) / 256, 256, 0, stream>>>(W2, W2h, W2l, HID_DIM, OUT_DIM);

    // xs16 = fp16(dinv * x)   (overwrites slot region -- slot dead after fill)
    xscale_kernel<<<(N_NODES * 32 + 255) / 256, 256, 0, stream>>>(x, dinv, xs16);
    // xa = A_norm @ x  via pre-scaled fp16 gather
    agg_kernel<false><<<AB, 256, 0, stream>>>((const uint4*)xs16, row_ptr, colv, dinv,
                                              nullptr, nullptr, nullptr, xa);
    // g16 = fp16(dinv * (relu(xa@W1+b1)@W2))
    fused_gemm_kernel<<<GB, 256, 0, stream>>>(xa, W1h, W1l, b1, W2h, W2l, dinv, g16, N_NODES);
    // out = LN(A_norm@g + b2)
    agg_kernel<true><<<AB, 256, 0, stream>>>((const uint4*)g16, row_ptr, colv, dinv,
                                             b2, gamma, beta, (float*)d_out);
}

// Round 6
// 393.683 us; speedup vs baseline: 2.1608x; 1.1415x over previous
//
#include <hip/hip_runtime.h>
#include <hip/hip_fp16.h>
#include <stdint.h>

#define N_NODES 100000
#define N_EDGES 1600000
#define IN_DIM  128
#define HID_DIM 256
#define OUT_DIM 128
#define RS 264   // padded LDS row stride (fp16 elems); rows differ by 4 banks -> 2-way max (free)

typedef __attribute__((ext_vector_type(8))) _Float16 f16x8;
typedef __attribute__((ext_vector_type(4))) float f32x4;

__device__ __forceinline__ int clampi(int v) {
    v = v < 0 ? 0 : v;
    return v >= N_NODES ? N_NODES - 1 : v;
}
__device__ __forceinline__ float2 h2f2(uint32_t u) {
    union { uint32_t u; __half2 h; } c; c.u = u;
    return __half22float2(c.h);
}
__device__ __forceinline__ uint32_t packh(float a, float b) {
    union { __half2 h; uint32_t u; } c; c.h = __floats2half2_rn(a, b);
    return c.u;
}
__device__ __forceinline__ uint16_t f2h(float a) {
    union { __half h; uint16_t s; } c; c.h = __float2half_rn(a);
    return c.s;
}

// ---------------- int64-vs-int32 edge_index detection ----------------

__global__ void detect_kernel(const int* __restrict__ ei, int* __restrict__ flag) {
    if (threadIdx.x == 0 && blockIdx.x == 0) {
        int z = 1;
        for (int i = 0; i < 16; ++i)
            if (ei[2 * i + 1] != 0) z = 0;
        flag[0] = z;
    }
}

__device__ __forceinline__ int src_at(const int* ei, int isI64, int e) {
    return clampi(isI64 ? ei[2 * (size_t)e] : ei[e]);
}
__device__ __forceinline__ int dst_at(const int* ei, int isI64, int e) {
    return clampi(isI64 ? ei[2 * (size_t)N_EDGES + 2 * (size_t)e]
                        : ei[(size_t)N_EDGES + e]);
}

// ---------------- CSR construction ----------------

__global__ __launch_bounds__(256) void count_kernel(const int* __restrict__ ei,
                                                    const int* __restrict__ flag,
                                                    int* __restrict__ cnt,
                                                    int* __restrict__ slot) {
    int e = blockIdx.x * 256 + threadIdx.x;
    if (e < N_EDGES) slot[e] = atomicAdd(&cnt[dst_at(ei, flag[0], e)], 1);
}

__global__ __launch_bounds__(256) void scan_a(const int* __restrict__ cnt,
                                              int* __restrict__ row_ptr,
                                              int* __restrict__ bsum, int n) {
    __shared__ int lds[256];
    int t = threadIdx.x, g = blockIdx.x * 256 + t;
    int v = (g < n) ? cnt[g] : 0;
    lds[t] = v; __syncthreads();
    for (int off = 1; off < 256; off <<= 1) {
        int x = (t >= off) ? lds[t - off] : 0;
        __syncthreads();
        if (t >= off) lds[t] += x;
        __syncthreads();
    }
    if (g < n) row_ptr[g] = lds[t] - v;     // exclusive
    if (t == 255) bsum[blockIdx.x] = lds[t];
}

__global__ __launch_bounds__(512) void scan_b(int* __restrict__ bsum, int nb) {
    __shared__ int lds[512];
    int t = threadIdx.x;
    int v = (t < nb) ? bsum[t] : 0;
    lds[t] = v; __syncthreads();
    for (int off = 1; off < 512; off <<= 1) {
        int x = (t >= off) ? lds[t - off] : 0;
        __syncthreads();
        if (t >= off) lds[t] += x;
        __syncthreads();
    }
    if (t < nb) bsum[t] = lds[t] - v;       // exclusive
}

__global__ __launch_bounds__(256) void scan_c(int* __restrict__ row_ptr,
                                              const int* __restrict__ bsum,
                                              int n, int total) {
    int g = blockIdx.x * 256 + threadIdx.x;
    if (g < n) row_ptr[g] += bsum[blockIdx.x];
    if (g == 0) row_ptr[n] = total;
}

__global__ __launch_bounds__(256) void finalize_kernel(const int* __restrict__ cnt,
                                                       float* __restrict__ dinv) {
    int i = blockIdx.x * 256 + threadIdx.x;
    if (i < N_NODES) dinv[i] = rsqrtf((float)(cnt[i] + 1));  // +1 self-loop
}

__global__ __launch_bounds__(256) void fill_kernel(const int* __restrict__ ei,
                                                   const int* __restrict__ flag,
                                                   const int* __restrict__ row_ptr,
                                                   const int* __restrict__ slot,
                                                   int* __restrict__ colv) {
    int e = blockIdx.x * 256 + threadIdx.x;
    if (e < N_EDGES) {
        int isI64 = flag[0];
        int d = dst_at(ei, isI64, e);
        colv[row_ptr[d] + slot[e]] = src_at(ei, isI64, e);   // no atomic
    }
}

// ---------------- weight transpose -> fp16 ----------------

__global__ __launch_bounds__(256) void wconv_kernel(const float* __restrict__ W,
                                                    uint16_t* __restrict__ Wt,
                                                    int K, int N) {
    int idx = blockIdx.x * 256 + threadIdx.x;
    if (idx < K * N) {
        int k = idx / N, n = idx - k * N;
        Wt[n * K + k] = f2h(W[idx]);
    }
}

// ---------------- x -> fp16 rows pre-scaled by dinv ----------------

__global__ __launch_bounds__(256) void xscale_kernel(const float* __restrict__ x,
                                                     const float* __restrict__ dinv,
                                                     uint32_t* __restrict__ xs16) {
    int idx = blockIdx.x * 256 + threadIdx.x;          // one float4 -> one uint2
    if (idx < N_NODES * 32) {
        float d = dinv[idx >> 5];
        float4 v = ((const float4*)x)[idx];
        uint2 o;
        o.x = packh(d * v.x, d * v.y);
        o.y = packh(d * v.z, d * v.w);
        ((uint2*)xs16)[idx] = o;
    }
}

// ---------------- normalized aggregation over fp16 pre-scaled rows ----------------
// rows[s] = dinv[s]*feat[s] (fp16). acc = sum_edges rows[s] + rows[node].
// F16OUT: out16[node] = fp16(dinv*acc) packed. LN: fp32 LayerNorm to out.
// 4 nodes/wave: 16 lanes x uint4(16B) = 256B row. Unroll-2 gather pipeline.

template<bool LN>
__global__ __launch_bounds__(256) void agg_kernel(const uint4* __restrict__ rows,
                                                  const int* __restrict__ row_ptr,
                                                  const int* __restrict__ colv,
                                                  const float* __restrict__ dinv,
                                                  const float* __restrict__ bias,
                                                  const float* __restrict__ gamma,
                                                  const float* __restrict__ beta,
                                                  float* __restrict__ out,
                                                  uint4* __restrict__ out16) {
    int node = blockIdx.x * 16 + (threadIdx.x >> 4);
    if (node >= N_NODES) return;
    int l = threadIdx.x & 15;
    float di = dinv[node];
    float acc[8];
    {
        uint4 u = rows[(size_t)node * 16 + l];
        float2 f0 = h2f2(u.x), f1 = h2f2(u.y), f2 = h2f2(u.z), f3 = h2f2(u.w);
        acc[0] = f0.x; acc[1] = f0.y; acc[2] = f1.x; acc[3] = f1.y;
        acc[4] = f2.x; acc[5] = f2.y; acc[6] = f3.x; acc[7] = f3.y;
    }
    int e = row_ptr[node], e1 = row_ptr[node + 1];
    int sa = (e < e1) ? colv[e] : 0;
    int sb = (e + 1 < e1) ? colv[e + 1] : 0;
    while (e + 2 <= e1) {
        uint4 va = rows[(size_t)clampi(sa) * 16 + l];
        uint4 vb = rows[(size_t)clampi(sb) * 16 + l];
        int na = (e + 2 < e1) ? colv[e + 2] : 0;
        int nb = (e + 3 < e1) ? colv[e + 3] : 0;
        {
            float2 f0 = h2f2(va.x), f1 = h2f2(va.y), f2 = h2f2(va.z), f3 = h2f2(va.w);
            acc[0] += f0.x; acc[1] += f0.y; acc[2] += f1.x; acc[3] += f1.y;
            acc[4] += f2.x; acc[5] += f2.y; acc[6] += f3.x; acc[7] += f3.y;
        }
        {
            float2 f0 = h2f2(vb.x), f1 = h2f2(vb.y), f2 = h2f2(vb.z), f3 = h2f2(vb.w);
            acc[0] += f0.x; acc[1] += f0.y; acc[2] += f1.x; acc[3] += f1.y;
            acc[4] += f2.x; acc[5] += f2.y; acc[6] += f3.x; acc[7] += f3.y;
        }
        sa = na; sb = nb; e += 2;
    }
    if (e < e1) {
        uint4 v = rows[(size_t)clampi(sa) * 16 + l];
        float2 f0 = h2f2(v.x), f1 = h2f2(v.y), f2 = h2f2(v.z), f3 = h2f2(v.w);
        acc[0] += f0.x; acc[1] += f0.y; acc[2] += f1.x; acc[3] += f1.y;
        acc[4] += f2.x; acc[5] += f2.y; acc[6] += f3.x; acc[7] += f3.y;
    }
    if (!LN) {
        // fp16 packed output, pre-scaled by di (feeds GEMM A directly)
        uint4 o;
        o.x = packh(acc[0] * di, acc[1] * di);
        o.y = packh(acc[2] * di, acc[3] * di);
        o.z = packh(acc[4] * di, acc[5] * di);
        o.w = packh(acc[6] * di, acc[7] * di);
        out16[(size_t)node * 16 + l] = o;
    } else {
        const float4* b4 = (const float4*)(bias + l * 8);
        float4 bb0 = b4[0], bb1 = b4[1];
        float v[8];
        v[0] = acc[0] * di + bb0.x; v[1] = acc[1] * di + bb0.y;
        v[2] = acc[2] * di + bb0.z; v[3] = acc[3] * di + bb0.w;
        v[4] = acc[4] * di + bb1.x; v[5] = acc[5] * di + bb1.y;
        v[6] = acc[6] * di + bb1.z; v[7] = acc[7] * di + bb1.w;
        float s = 0.f;
        #pragma unroll
        for (int j = 0; j < 8; ++j) s += v[j];
        #pragma unroll
        for (int o = 8; o > 0; o >>= 1) s += __shfl_xor(s, o, 64);   // 16-lane group
        float mu = s * (1.0f / 128.0f);
        float q = 0.f;
        #pragma unroll
        for (int j = 0; j < 8; ++j) { v[j] -= mu; q += v[j] * v[j]; }
        #pragma unroll
        for (int o = 8; o > 0; o >>= 1) q += __shfl_xor(q, o, 64);
        float rstd = rsqrtf(q * (1.0f / 128.0f) + 1e-5f);
        const float4* g4 = (const float4*)(gamma + l * 8);
        const float4* t4 = (const float4*)(beta + l * 8);
        float4 g0 = g4[0], g1 = g4[1], t0 = t4[0], t1 = t4[1];
        float* orow = out + (size_t)node * 128 + l * 8;
        float4 o0, o1;
        o0.x = v[0] * rstd * g0.x + t0.x; o0.y = v[1] * rstd * g0.y + t0.y;
        o0.z = v[2] * rstd * g0.z + t0.z; o0.w = v[3] * rstd * g0.w + t0.w;
        o1.x = v[4] * rstd * g1.x + t1.x; o1.y = v[5] * rstd * g1.y + t1.y;
        o1.z = v[6] * rstd * g1.z + t1.z; o1.w = v[7] * rstd * g1.w + t1.w;
        *(float4*)orow = o0; *(float4*)(orow + 4) = o1;
    }
}

// ---------------- fused GEMM1(+bias+relu)+GEMM2, fp16 MFMA ----------------
// A16: fp16 [M,128] (already dinv-free: agg1 pre-scaled). Block = 64 rows, 4 waves.
// Phase 1: wave w computes h cols [w*64,w*64+64) for 64 rows (4 m-tiles, B-frag
// reuse -> 4x ILP). h fp16 in block LDS (33.8 KB -> 4 blocks/CU). Phase 2: wave w
// computes G cols [w*32,w*32+32); W2 frags in regs, h streamed via ds_read_b128.
// G16[row] = fp16(dinv[row] * G[row]) -- pre-scaled for agg2.

__global__ __launch_bounds__(256) void fused_gemm_kernel(const uint16_t* __restrict__ A16,
                                                         const uint16_t* __restrict__ W1t,
                                                         const float* __restrict__ b1,
                                                         const uint16_t* __restrict__ W2t,
                                                         const float* __restrict__ dinv,
                                                         uint16_t* __restrict__ G16, int M) {
    __shared__ __align__(16) uint16_t Hs[64 * RS];   // 33792 B
    int lane = threadIdx.x & 63;
    int wave = threadIdx.x >> 6;
    int r15 = lane & 15;
    int quad = lane >> 4;
    int kofs = quad * 8;
    int blk_row = blockIdx.x * 64;

    // A-frags, 4 m-tiles: A[m=r15][k=quad*8+j], one b128 load each
    f16x8 a[4][4];
    #pragma unroll
    for (int mt = 0; mt < 4; ++mt) {
        bool valid = (blk_row + mt * 16) < M;        // M%16==0: tile all-valid or not
        int row = valid ? (blk_row + mt * 16 + r15) : 0;
        const uint16_t* arow = A16 + (size_t)row * IN_DIM + kofs;
        #pragma unroll
        for (int ks = 0; ks < 4; ++ks)
            a[mt][ks] = *(const f16x8*)(arow + ks * 32);
    }

    // phase 1: h = relu(A@W1+b1), wave's 4 nt-tiles (64 cols)
    #pragma unroll
    for (int nt = 0; nt < 4; ++nt) {
        int ncol = (wave * 4 + nt) * 16 + r15;       // 0..255
        const uint16_t* bp = W1t + (size_t)ncol * IN_DIM + kofs;
        f32x4 acc[4];
        #pragma unroll
        for (int mt = 0; mt < 4; ++mt) acc[mt] = (f32x4){0.f, 0.f, 0.f, 0.f};
        #pragma unroll
        for (int ks = 0; ks < 4; ++ks) {
            f16x8 bv = *(const f16x8*)(bp + ks * 32);
            #pragma unroll
            for (int mt = 0; mt < 4; ++mt)
                acc[mt] = __builtin_amdgcn_mfma_f32_16x16x32_f16(a[mt][ks], bv, acc[mt], 0, 0, 0);
        }
        float bb = b1[ncol];
        #pragma unroll
        for (int mt = 0; mt < 4; ++mt) {
            #pragma unroll
            for (int r = 0; r < 4; ++r) {            // C/D: col=lane&15, row=quad*4+r
                int lrow = mt * 16 + quad * 4 + r;
                Hs[lrow * RS + ncol] = f2h(fmaxf(acc[mt][r] + bb, 0.f));
            }
        }
    }
    __syncthreads();

    // phase 2: G = h@W2, wave's 2 nt-tiles (32 cols), all 4 m-tiles
    #pragma unroll
    for (int nt = 0; nt < 2; ++nt) {
        int ncol = (wave * 2 + nt) * 16 + r15;       // 0..127
        const uint16_t* bp = W2t + (size_t)ncol * HID_DIM + kofs;
        f16x8 b2[8];
        #pragma unroll
        for (int ks = 0; ks < 8; ++ks)
            b2[ks] = *(const f16x8*)(bp + ks * 32);
        f32x4 acc[4];
        #pragma unroll
        for (int mt = 0; mt < 4; ++mt) acc[mt] = (f32x4){0.f, 0.f, 0.f, 0.f};
        #pragma unroll
        for (int ks = 0; ks < 8; ++ks) {
            #pragma unroll
            for (int mt = 0; mt < 4; ++mt) {
                f16x8 av = *(const f16x8*)(Hs + (mt * 16 + r15) * RS + ks * 32 + kofs);
                acc[mt] = __builtin_amdgcn_mfma_f32_16x16x32_f16(av, b2[ks], acc[mt], 0, 0, 0);
            }
        }
        #pragma unroll
        for (int mt = 0; mt < 4; ++mt) {
            if ((blk_row + mt * 16) < M) {
                #pragma unroll
                for (int r = 0; r < 4; ++r) {
                    int row = blk_row + mt * 16 + quad * 4 + r;
                    G16[(size_t)row * OUT_DIM + ncol] = f2h(dinv[row] * acc[mt][r]);
                }
            }
        }
    }
}

// ---------------- launch ----------------

extern "C" void kernel_launch(void* const* d_in, const int* in_sizes, int n_in,
                              void* d_out, int out_size, void* d_ws, size_t ws_size,
                              hipStream_t stream) {
    const float* x     = (const float*)d_in[0];   // fp32 [100000,128]
    const int*   ei    = (const int*)d_in[1];     // int32 or int64 [2,1.6M]
    const float* W1    = (const float*)d_in[2];
    const float* b1    = (const float*)d_in[3];
    const float* W2    = (const float*)d_in[4];
    const float* b2    = (const float*)d_in[5];
    const float* gamma = (const float*)d_in[6];
    const float* beta  = (const float*)d_in[7];

    char* ws = (char*)d_ws;
    size_t off = 0;
    auto alloc = [&](size_t bytes) -> void* {
        void* p = ws + off;
        off += (bytes + 511) & ~(size_t)511;
        return p;
    };
    int*      cnt     = (int*)alloc((size_t)N_NODES * 4);
    int*      row_ptr = (int*)alloc((size_t)(N_NODES + 1) * 4);
    float*    dinv    = (float*)alloc((size_t)N_NODES * 4);
    int*      bsum    = (int*)alloc(512 * 4);
    int*      flag    = (int*)alloc(4);
    uint16_t* W1t     = (uint16_t*)alloc((size_t)IN_DIM * HID_DIM * 2);
    uint16_t* W2t     = (uint16_t*)alloc((size_t)HID_DIM * OUT_DIM * 2);
    int*      colv    = (int*)alloc((size_t)N_EDGES * 4);
    // big region (25.6 MB), sequentially reused: slot -> xs16 -> g16
    void*     big     = alloc((size_t)N_NODES * IN_DIM * 2);
    int*      slot    = (int*)big;            // dead after fill
    uint32_t* xs16    = (uint32_t*)big;       // dead after agg1
    uint16_t* g16     = (uint16_t*)big;       // written by gemm, read by agg2
    if (ws_size < off) return;   // "ws too small" signature: absmax == max|ref|

    uint16_t* xa16 = (uint16_t*)d_out;  // fp16 A matrix in d_out scratch (25.6 of 51.2 MB)

    const int EB = (N_EDGES + 255) / 256;
    const int NB = (N_NODES + 255) / 256;
    const int AB = (N_NODES + 15) / 16;    // 16 nodes/block (4 per wave)
    const int GB = (N_NODES + 63) / 64;

    detect_kernel<<<1, 64, 0, stream>>>(ei, flag);
    hipMemsetAsync(cnt, 0, (size_t)N_NODES * 4, stream);
    count_kernel<<<EB, 256, 0, stream>>>(ei, flag, cnt, slot);
    scan_a<<<NB, 256, 0, stream>>>(cnt, row_ptr, bsum, N_NODES);
    scan_b<<<1, 512, 0, stream>>>(bsum, NB);
    scan_c<<<NB, 256, 0, stream>>>(row_ptr, bsum, N_NODES, N_EDGES);
    finalize_kernel<<<NB, 256, 0, stream>>>(cnt, dinv);
    fill_kernel<<<EB, 256, 0, stream>>>(ei, flag, row_ptr, slot, colv);

    wconv_kernel<<<(IN_DIM * HID_DIM + 255) / 256, 256, 0, stream>>>(W1, W1t, IN_DIM, HID_DIM);
    wconv_kernel<<<(HID_DIM * OUT_DIM + 255) / 256, 256, 0, stream>>>(W2, W2t, HID_DIM, OUT_DIM);

    // xs16 = fp16(dinv * x)
    xscale_kernel<<<(N_NODES * 32 + 255) / 256, 256, 0, stream>>>(x, dinv, xs16);
    // xa16 = fp16(A_norm @ x)  (packed fp16 into d_out scratch)
    agg_kernel<false><<<AB, 256, 0, stream>>>((const uint4*)xs16, row_ptr, colv, dinv,
                                              nullptr, nullptr, nullptr,
                                              nullptr, (uint4*)xa16);
    // g16 = fp16(dinv * (relu(xa@W1+b1)@W2))
    fused_gemm_kernel<<<GB, 256, 0, stream>>>(xa16, W1t, b1, W2t, dinv, g16, N_NODES);
    // out = LN(A_norm@g + b2)
    agg_kernel<true><<<AB, 256, 0, stream>>>((const uint4*)g16, row_ptr, colv, dinv,
                                             b2, gamma, beta, (float*)d_out, nullptr);
}

// Round 7
// 351.829 us; speedup vs baseline: 2.4179x; 1.1190x over previous
//
#include <hip/hip_runtime.h>
#include <hip/hip_fp16.h>
#include <stdint.h>

#define N_NODES 100000
#define N_EDGES 1600000
#define IN_DIM  128
#define HID_DIM 256
#define OUT_DIM 128
#define RS 264     // padded LDS row stride (fp16 elems) in GEMM
#define NBUCK 391  // buckets of 256 nodes: dst>>8 in [0,390]
#define EPB   4096 // edges per partition block
#define PADB  5120 // padded records per bucket (mean 4092, +16 sigma)

typedef __attribute__((ext_vector_type(8))) _Float16 f16x8;
typedef __attribute__((ext_vector_type(4))) float f32x4;

__device__ __forceinline__ int clampi(int v) {
    v = v < 0 ? 0 : v;
    return v >= N_NODES ? N_NODES - 1 : v;
}
__device__ __forceinline__ float2 h2f2(uint32_t u) {
    union { uint32_t u; __half2 h; } c; c.u = u;
    return __half22float2(c.h);
}
__device__ __forceinline__ uint32_t packh(float a, float b) {
    union { __half2 h; uint32_t u; } c; c.h = __floats2half2_rn(a, b);
    return c.u;
}
__device__ __forceinline__ uint16_t f2h(float a) {
    union { __half h; uint16_t s; } c; c.h = __float2half_rn(a);
    return c.s;
}

// ---------------- int64-vs-int32 edge_index detection ----------------

__global__ void detect_kernel(const int* __restrict__ ei, int* __restrict__ flag) {
    if (threadIdx.x == 0 && blockIdx.x == 0) {
        int z = 1;
        for (int i = 0; i < 16; ++i)
            if (ei[2 * i + 1] != 0) z = 0;
        flag[0] = z;
    }
}

__device__ __forceinline__ int src_at(const int* ei, int isI64, int e) {
    return clampi(isI64 ? ei[2 * (size_t)e] : ei[e]);
}
__device__ __forceinline__ int dst_at(const int* ei, int isI64, int e) {
    return clampi(isI64 ? ei[2 * (size_t)N_EDGES + 2 * (size_t)e]
                        : ei[(size_t)N_EDGES + e]);
}

// ---------------- bucket-radix CSR build ----------------
// partition: per-block LDS histogram over 391 dst-buckets, one global atomic
// per (block,bucket), records staged bucket-major in LDS, coalesced write-out.

__global__ __launch_bounds__(256) void partition_kernel(const int* __restrict__ ei,
                                                        const int* __restrict__ flag,
                                                        int* __restrict__ cursor,
                                                        uint2* __restrict__ recs) {
    __shared__ int hist[NBUCK];
    __shared__ int histBase[NBUCK];
    __shared__ int gBase[NBUCK];
    __shared__ int scanT[512];
    __shared__ uint2 lrec[EPB];        // 32 KB
    int tid = threadIdx.x;
    int isI64 = flag[0];
    for (int b = tid; b < NBUCK; b += 256) hist[b] = 0;
    __syncthreads();
    int base = blockIdx.x * EPB;
    int srcs[16], dsts[16], slots[16];
    #pragma unroll
    for (int r = 0; r < 16; ++r) {
        int e = base + r * 256 + tid;
        slots[r] = -1;
        srcs[r] = 0; dsts[r] = 0;
        if (e < N_EDGES) {
            srcs[r] = src_at(ei, isI64, e);
            dsts[r] = dst_at(ei, isI64, e);
            slots[r] = atomicAdd(&hist[dsts[r] >> 8], 1);
        }
    }
    __syncthreads();
    // exclusive scan of hist (391) via 512-wide Hillis-Steele, 2 elems/thread
    scanT[tid]       = (tid < NBUCK) ? hist[tid] : 0;
    scanT[tid + 256] = (tid + 256 < NBUCK) ? hist[tid + 256] : 0;
    __syncthreads();
    for (int off = 1; off < 512; off <<= 1) {
        int v0 = (tid >= off) ? scanT[tid - off] : 0;
        int v1 = scanT[tid + 256 - off];
        __syncthreads();
        if (tid >= off) scanT[tid] += v0;
        scanT[tid + 256] += v1;
        __syncthreads();
    }
    for (int b = tid; b < NBUCK; b += 256) {
        histBase[b] = b ? scanT[b - 1] : 0;
        if (hist[b] > 0) gBase[b] = atomicAdd(&cursor[b], hist[b]);
    }
    __syncthreads();
    // scatter records into LDS, bucket-major
    #pragma unroll
    for (int r = 0; r < 16; ++r) {
        if (slots[r] >= 0) {
            int b = dsts[r] >> 8;
            uint2 rec; rec.x = (unsigned)srcs[r]; rec.y = (unsigned)dsts[r];
            lrec[histBase[b] + slots[r]] = rec;
        }
    }
    __syncthreads();
    // linear write-out: consecutive threads -> same-bucket runs -> coalesced
    int nvalid = N_EDGES - base; if (nvalid > EPB) nvalid = EPB;
    for (int i = tid; i < nvalid; i += 256) {
        uint2 rec = lrec[i];
        int b = (int)(rec.y >> 8);
        int pos = gBase[b] + (i - histBase[b]);
        if (pos < PADB)
            recs[(size_t)b * PADB + pos] = rec;
    }
}

__global__ __launch_bounds__(512) void bucket_scan(const int* __restrict__ cursor,
                                                   int* __restrict__ csrBase,
                                                   int* __restrict__ row_ptr) {
    __shared__ int lds[512];
    int t = threadIdx.x;
    int v = 0;
    if (t < NBUCK) { v = cursor[t]; if (v > PADB) v = PADB; }
    lds[t] = v; __syncthreads();
    for (int off = 1; off < 512; off <<= 1) {
        int x = (t >= off) ? lds[t - off] : 0;
        __syncthreads();
        if (t >= off) lds[t] += x;
        __syncthreads();
    }
    if (t < NBUCK) csrBase[t] = lds[t] - v;       // exclusive
    if (t == NBUCK - 1) row_ptr[N_NODES] = lds[t];
}

// build: one block per bucket; LDS histogram -> degrees/row_ptr/dinv; LDS-atomic
// slots -> colv (writes land in a ~17KB hot region -> L2 write-combined).

__global__ __launch_bounds__(256) void build_kernel(const uint2* __restrict__ recs,
                                                    const int* __restrict__ cursor,
                                                    const int* __restrict__ csrBase,
                                                    int* __restrict__ row_ptr,
                                                    float* __restrict__ dinv,
                                                    int* __restrict__ colv) {
    __shared__ uint2 lrec[PADB];       // 40 KB
    __shared__ int cnt[256];
    __shared__ int lofs[256];
    __shared__ int cur[256];
    __shared__ int scanT[256];
    int b = blockIdx.x, tid = threadIdx.x;
    int nb = cursor[b]; if (nb > PADB) nb = PADB;
    cnt[tid] = 0; cur[tid] = 0;
    __syncthreads();
    for (int i = tid; i < nb; i += 256) {
        uint2 r = recs[(size_t)b * PADB + i];
        lrec[i] = r;
        atomicAdd(&cnt[r.y & 255], 1);
    }
    __syncthreads();
    scanT[tid] = cnt[tid];
    __syncthreads();
    for (int off = 1; off < 256; off <<= 1) {
        int x = (tid >= off) ? scanT[tid - off] : 0;
        __syncthreads();
        if (tid >= off) scanT[tid] += x;
        __syncthreads();
    }
    lofs[tid] = tid ? scanT[tid - 1] : 0;
    int cbase = csrBase[b];
    int node = b * 256 + tid;
    if (node < N_NODES) {
        row_ptr[node] = cbase + lofs[tid];
        dinv[node] = rsqrtf((float)(cnt[tid] + 1));   // +1 self-loop
    }
    __syncthreads();
    for (int i = tid; i < nb; i += 256) {
        uint2 r = lrec[i];
        int id = (int)(r.y & 255);
        int slot = atomicAdd(&cur[id], 1);
        colv[cbase + lofs[id] + slot] = (int)r.x;
    }
}

// ---------------- weight transpose -> fp16 ----------------

__global__ __launch_bounds__(256) void wconv_kernel(const float* __restrict__ W,
                                                    uint16_t* __restrict__ Wt,
                                                    int K, int N) {
    int idx = blockIdx.x * 256 + threadIdx.x;
    if (idx < K * N) {
        int k = idx / N, n = idx - k * N;
        Wt[n * K + k] = f2h(W[idx]);
    }
}

// ---------------- x -> fp16 rows pre-scaled by dinv ----------------

__global__ __launch_bounds__(256) void xscale_kernel(const float* __restrict__ x,
                                                     const float* __restrict__ dinv,
                                                     uint32_t* __restrict__ xs16) {
    int idx = blockIdx.x * 256 + threadIdx.x;          // one float4 -> one uint2
    if (idx < N_NODES * 32) {
        float d = dinv[idx >> 5];
        float4 v = ((const float4*)x)[idx];
        uint2 o;
        o.x = packh(d * v.x, d * v.y);
        o.y = packh(d * v.z, d * v.w);
        ((uint2*)xs16)[idx] = o;
    }
}

// ---------------- normalized aggregation over fp16 pre-scaled rows ----------------
// rows[s] = dinv[s]*feat[s] (fp16). acc = sum_edges rows[s] + rows[node].
// !LN: out16 = fp16(dinv*acc). LN: fp32 LayerNorm -> out.
// 4 nodes/wave: 16 lanes x uint4 = 256B row. Unroll-2 gather pipeline.

template<bool LN>
__global__ __launch_bounds__(256) void agg_kernel(const uint4* __restrict__ rows,
                                                  const int* __restrict__ row_ptr,
                                                  const int* __restrict__ colv,
                                                  const float* __restrict__ dinv,
                                                  const float* __restrict__ bias,
                                                  const float* __restrict__ gamma,
                                                  const float* __restrict__ beta,
                                                  float* __restrict__ out,
                                                  uint4* __restrict__ out16) {
    int node = blockIdx.x * 16 + (threadIdx.x >> 4);
    if (node >= N_NODES) return;
    int l = threadIdx.x & 15;
    float di = dinv[node];
    float acc[8];
    {
        uint4 u = rows[(size_t)node * 16 + l];
        float2 f0 = h2f2(u.x), f1 = h2f2(u.y), f2 = h2f2(u.z), f3 = h2f2(u.w);
        acc[0] = f0.x; acc[1] = f0.y; acc[2] = f1.x; acc[3] = f1.y;
        acc[4] = f2.x; acc[5] = f2.y; acc[6] = f3.x; acc[7] = f3.y;
    }
    int e = row_ptr[node], e1 = row_ptr[node + 1];
    int sa = (e < e1) ? colv[e] : 0;
    int sb = (e + 1 < e1) ? colv[e + 1] : 0;
    while (e + 2 <= e1) {
        uint4 va = rows[(size_t)clampi(sa) * 16 + l];
        uint4 vb = rows[(size_t)clampi(sb) * 16 + l];
        int na = (e + 2 < e1) ? colv[e + 2] : 0;
        int nb = (e + 3 < e1) ? colv[e + 3] : 0;
        {
            float2 f0 = h2f2(va.x), f1 = h2f2(va.y), f2 = h2f2(va.z), f3 = h2f2(va.w);
            acc[0] += f0.x; acc[1] += f0.y; acc[2] += f1.x; acc[3] += f1.y;
            acc[4] += f2.x; acc[5] += f2.y; acc[6] += f3.x; acc[7] += f3.y;
        }
        {
            float2 f0 = h2f2(vb.x), f1 = h2f2(vb.y), f2 = h2f2(vb.z), f3 = h2f2(vb.w);
            acc[0] += f0.x; acc[1] += f0.y; acc[2] += f1.x; acc[3] += f1.y;
            acc[4] += f2.x; acc[5] += f2.y; acc[6] += f3.x; acc[7] += f3.y;
        }
        sa = na; sb = nb; e += 2;
    }
    if (e < e1) {
        uint4 v = rows[(size_t)clampi(sa) * 16 + l];
        float2 f0 = h2f2(v.x), f1 = h2f2(v.y), f2 = h2f2(v.z), f3 = h2f2(v.w);
        acc[0] += f0.x; acc[1] += f0.y; acc[2] += f1.x; acc[3] += f1.y;
        acc[4] += f2.x; acc[5] += f2.y; acc[6] += f3.x; acc[7] += f3.y;
    }
    if (!LN) {
        uint4 o;
        o.x = packh(acc[0] * di, acc[1] * di);
        o.y = packh(acc[2] * di, acc[3] * di);
        o.z = packh(acc[4] * di, acc[5] * di);
        o.w = packh(acc[6] * di, acc[7] * di);
        out16[(size_t)node * 16 + l] = o;
    } else {
        const float4* b4 = (const float4*)(bias + l * 8);
        float4 bb0 = b4[0], bb1 = b4[1];
        float v[8];
        v[0] = acc[0] * di + bb0.x; v[1] = acc[1] * di + bb0.y;
        v[2] = acc[2] * di + bb0.z; v[3] = acc[3] * di + bb0.w;
        v[4] = acc[4] * di + bb1.x; v[5] = acc[5] * di + bb1.y;
        v[6] = acc[6] * di + bb1.z; v[7] = acc[7] * di + bb1.w;
        float s = 0.f;
        #pragma unroll
        for (int j = 0; j < 8; ++j) s += v[j];
        #pragma unroll
        for (int o = 8; o > 0; o >>= 1) s += __shfl_xor(s, o, 64);   // 16-lane group
        float mu = s * (1.0f / 128.0f);
        float q = 0.f;
        #pragma unroll
        for (int j = 0; j < 8; ++j) { v[j] -= mu; q += v[j] * v[j]; }
        #pragma unroll
        for (int o = 8; o > 0; o >>= 1) q += __shfl_xor(q, o, 64);
        float rstd = rsqrtf(q * (1.0f / 128.0f) + 1e-5f);
        const float4* g4 = (const float4*)(gamma + l * 8);
        const float4* t4 = (const float4*)(beta + l * 8);
        float4 g0 = g4[0], g1 = g4[1], t0 = t4[0], t1 = t4[1];
        float* orow = out + (size_t)node * 128 + l * 8;
        float4 o0, o1;
        o0.x = v[0] * rstd * g0.x + t0.x; o0.y = v[1] * rstd * g0.y + t0.y;
        o0.z = v[2] * rstd * g0.z + t0.z; o0.w = v[3] * rstd * g0.w + t0.w;
        o1.x = v[4] * rstd * g1.x + t1.x; o1.y = v[5] * rstd * g1.y + t1.y;
        o1.z = v[6] * rstd * g1.z + t1.z; o1.w = v[7] * rstd * g1.w + t1.w;
        *(float4*)orow = o0; *(float4*)(orow + 4) = o1;
    }
}

// ---------------- fused GEMM1(+bias+relu)+GEMM2, fp16 MFMA ----------------

__global__ __launch_bounds__(256) void fused_gemm_kernel(const uint16_t* __restrict__ A16,
                                                         const uint16_t* __restrict__ W1t,
                                                         const float* __restrict__ b1,
                                                         const uint16_t* __restrict__ W2t,
                                                         const float* __restrict__ dinv,
                                                         uint16_t* __restrict__ G16, int M) {
    __shared__ __align__(16) uint16_t Hs[64 * RS];   // 33792 B
    int lane = threadIdx.x & 63;
    int wave = threadIdx.x >> 6;
    int r15 = lane & 15;
    int quad = lane >> 4;
    int kofs = quad * 8;
    int blk_row = blockIdx.x * 64;

    f16x8 a[4][4];
    #pragma unroll
    for (int mt = 0; mt < 4; ++mt) {
        bool valid = (blk_row + mt * 16) < M;
        int row = valid ? (blk_row + mt * 16 + r15) : 0;
        const uint16_t* arow = A16 + (size_t)row * IN_DIM + kofs;
        #pragma unroll
        for (int ks = 0; ks < 4; ++ks)
            a[mt][ks] = *(const f16x8*)(arow + ks * 32);
    }

    #pragma unroll
    for (int nt = 0; nt < 4; ++nt) {
        int ncol = (wave * 4 + nt) * 16 + r15;
        const uint16_t* bp = W1t + (size_t)ncol * IN_DIM + kofs;
        f32x4 acc[4];
        #pragma unroll
        for (int mt = 0; mt < 4; ++mt) acc[mt] = (f32x4){0.f, 0.f, 0.f, 0.f};
        #pragma unroll
        for (int ks = 0; ks < 4; ++ks) {
            f16x8 bv = *(const f16x8*)(bp + ks * 32);
            #pragma unroll
            for (int mt = 0; mt < 4; ++mt)
                acc[mt] = __builtin_amdgcn_mfma_f32_16x16x32_f16(a[mt][ks], bv, acc[mt], 0, 0, 0);
        }
        float bb = b1[ncol];
        #pragma unroll
        for (int mt = 0; mt < 4; ++mt) {
            #pragma unroll
            for (int r = 0; r < 4; ++r) {
                int lrow = mt * 16 + quad * 4 + r;
                Hs[lrow * RS + ncol] = f2h(fmaxf(acc[mt][r] + bb, 0.f));
            }
        }
    }
    __syncthreads();

    #pragma unroll
    for (int nt = 0; nt < 2; ++nt) {
        int ncol = (wave * 2 + nt) * 16 + r15;
        const uint16_t* bp = W2t + (size_t)ncol * HID_DIM + kofs;
        f16x8 b2[8];
        #pragma unroll
        for (int ks = 0; ks < 8; ++ks)
            b2[ks] = *(const f16x8*)(bp + ks * 32);
        f32x4 acc[4];
        #pragma unroll
        for (int mt = 0; mt < 4; ++mt) acc[mt] = (f32x4){0.f, 0.f, 0.f, 0.f};
        #pragma unroll
        for (int ks = 0; ks < 8; ++ks) {
            #pragma unroll
            for (int mt = 0; mt < 4; ++mt) {
                f16x8 av = *(const f16x8*)(Hs + (mt * 16 + r15) * RS + ks * 32 + kofs);
                acc[mt] = __builtin_amdgcn_mfma_f32_16x16x32_f16(av, b2[ks], acc[mt], 0, 0, 0);
            }
        }
        #pragma unroll
        for (int mt = 0; mt < 4; ++mt) {
            if ((blk_row + mt * 16) < M) {
                #pragma unroll
                for (int r = 0; r < 4; ++r) {
                    int row = blk_row + mt * 16 + quad * 4 + r;
                    G16[(size_t)row * OUT_DIM + ncol] = f2h(dinv[row] * acc[mt][r]);
                }
            }
        }
    }
}

// ---------------- launch ----------------

extern "C" void kernel_launch(void* const* d_in, const int* in_sizes, int n_in,
                              void* d_out, int out_size, void* d_ws, size_t ws_size,
                              hipStream_t stream) {
    const float* x     = (const float*)d_in[0];   // fp32 [100000,128]
    const int*   ei    = (const int*)d_in[1];     // int32 or int64 [2,1.6M]
    const float* W1    = (const float*)d_in[2];
    const float* b1    = (const float*)d_in[3];
    const float* W2    = (const float*)d_in[4];
    const float* b2    = (const float*)d_in[5];
    const float* gamma = (const float*)d_in[6];
    const float* beta  = (const float*)d_in[7];

    char* ws = (char*)d_ws;
    size_t off = 0;
    auto alloc = [&](size_t bytes) -> void* {
        void* p = ws + off;
        off += (bytes + 511) & ~(size_t)511;
        return p;
    };
    int*      cursor  = (int*)alloc((size_t)NBUCK * 4);
    int*      csrBase = (int*)alloc((size_t)NBUCK * 4);
    int*      row_ptr = (int*)alloc((size_t)(N_NODES + 1) * 4);
    float*    dinv    = (float*)alloc((size_t)N_NODES * 4);
    int*      flag    = (int*)alloc(4);
    uint16_t* W1t     = (uint16_t*)alloc((size_t)IN_DIM * HID_DIM * 2);
    uint16_t* W2t     = (uint16_t*)alloc((size_t)HID_DIM * OUT_DIM * 2);
    int*      colv    = (int*)alloc((size_t)N_EDGES * 4);
    // big region (25.6 MB), sequentially reused: recs -> xs16 -> g16
    void*     big     = alloc((size_t)N_NODES * IN_DIM * 2);
    uint2*    recs    = (uint2*)big;          // 16.0 MB, dead after build
    uint32_t* xs16    = (uint32_t*)big;       // dead after agg1
    uint16_t* g16     = (uint16_t*)big;       // written by gemm, read by agg2
    if (ws_size < off) return;   // "ws too small" signature: absmax == max|ref|

    uint16_t* xa16 = (uint16_t*)d_out;  // fp16 A matrix in d_out scratch

    const int PB = (N_EDGES + EPB - 1) / EPB;   // 391
    const int AB = (N_NODES + 15) / 16;
    const int GB = (N_NODES + 63) / 64;

    detect_kernel<<<1, 64, 0, stream>>>(ei, flag);
    hipMemsetAsync(cursor, 0, (size_t)NBUCK * 4, stream);
    partition_kernel<<<PB, 256, 0, stream>>>(ei, flag, cursor, recs);
    bucket_scan<<<1, 512, 0, stream>>>(cursor, csrBase, row_ptr);
    build_kernel<<<NBUCK, 256, 0, stream>>>(recs, cursor, csrBase, row_ptr, dinv, colv);

    wconv_kernel<<<(IN_DIM * HID_DIM + 255) / 256, 256, 0, stream>>>(W1, W1t, IN_DIM, HID_DIM);
    wconv_kernel<<<(HID_DIM * OUT_DIM + 255) / 256, 256, 0, stream>>>(W2, W2t, HID_DIM, OUT_DIM);

    // xs16 = fp16(dinv * x)  (overwrites recs region -- recs dead after build)
    xscale_kernel<<<(N_NODES * 32 + 255) / 256, 256, 0, stream>>>(x, dinv, xs16);
    // xa16 = fp16(A_norm @ x)
    agg_kernel<false><<<AB, 256, 0, stream>>>((const uint4*)xs16, row_ptr, colv, dinv,
                                              nullptr, nullptr, nullptr,
                                              nullptr, (uint4*)xa16);
    // g16 = fp16(dinv * (relu(xa@W1+b1)@W2))
    fused_gemm_kernel<<<GB, 256, 0, stream>>>(xa16, W1t, b1, W2t, dinv, g16, N_NODES);
    // out = LN(A_norm@g + b2)
    agg_kernel<true><<<AB, 256, 0, stream>>>((const uint4*)g16, row_ptr, colv, dinv,
                                             b2, gamma, beta, (float*)d_out, nullptr);
}